// Round 8
// baseline (773.321 us; speedup 1.0000x reference)
//
#include <hip/hip_runtime.h>

typedef unsigned short u16;
typedef unsigned int u32;
typedef __attribute__((ext_vector_type(4))) float f32x4;
typedef __attribute__((ext_vector_type(16))) float f32x16;
typedef __attribute__((ext_vector_type(8))) short bf16x8;

// Problem sizes (fixed): B=2, S=2048, D=2048, NH=16, NKV=4, HD=128

__device__ __forceinline__ u16 f2b(float f) {
  u32 u = __builtin_bit_cast(u32, f);
  u = (u + 0x7fffu + ((u >> 16) & 1u)) >> 16;  // RNE
  return (u16)u;
}

__device__ __forceinline__ void gload_lds16(const void* g, void* l) {
  __builtin_amdgcn_global_load_lds((const __attribute__((address_space(1))) u32*)g,
                                   (__attribute__((address_space(3))) u32*)l, 16, 0, 0);
}

// ---- cross-half (lane <-> lane^32) exchange via v_permlane32_swap_b32 (VALU pipe) ----
#if __has_builtin(__builtin_amdgcn_permlane32_swap)
#define HAS_PLS 1
__device__ __forceinline__ void pls(u32 x, u32 y, u32& rx, u32& ry) {
  auto r = __builtin_amdgcn_permlane32_swap(x, y, false, false);
  rx = (u32)r[0];
  ry = (u32)r[1];
}
#endif

__device__ __forceinline__ float xhalf_max(float v) {
#ifdef HAS_PLS
  u32 a, b;
  pls(__builtin_bit_cast(u32, v), __builtin_bit_cast(u32, v), a, b);
  return fmaxf(__builtin_bit_cast(float, a), __builtin_bit_cast(float, b));
#else
  return fmaxf(v, __shfl_xor(v, 32));
#endif
}

__device__ __forceinline__ float xhalf_sum(float v) {
#ifdef HAS_PLS
  u32 a, b;
  pls(__builtin_bit_cast(u32, v), __builtin_bit_cast(u32, v), a, b);
  return __builtin_bit_cast(float, a) + __builtin_bit_cast(float, b);
#else
  return v + __shfl_xor(v, 32);
#endif
}

// P-fragment redistribution across lane halves
__device__ __forceinline__ void xexchange(int hi, u32 a0, u32 a1, u32 a2, u32 a3, u32* o) {
#ifdef HAS_PLS
  pls(a0, a2, o[0], o[2]);
  pls(a1, a3, o[1], o[3]);
#else
  u32 xa0 = (u32)__shfl_xor((int)a0, 32), xa1 = (u32)__shfl_xor((int)a1, 32);
  u32 xa2 = (u32)__shfl_xor((int)a2, 32), xa3 = (u32)__shfl_xor((int)a3, 32);
  o[0] = hi ? xa2 : a0;
  o[1] = hi ? xa3 : a1;
  o[2] = hi ? a2 : xa0;
  o[3] = hi ? a3 : xa1;
#endif
}

// truncating bf16 pair pack (P in [0,1]; <=2^-8 rel err, cheap: 3 ops)
__device__ __forceinline__ u32 pktrunc(float lo, float hif) {
  return (__builtin_bit_cast(u32, lo) >> 16) | (__builtin_bit_cast(u32, hif) & 0xffff0000u);
}

// ---------------- fp32 -> bf16 conversion ----------------
__global__ void cvt_bf16(const float* __restrict__ src, u16* __restrict__ dst, int n) {
  int stride = gridDim.x * blockDim.x * 4;
  for (int idx = (blockIdx.x * blockDim.x + threadIdx.x) * 4; idx < n; idx += stride) {
    float4 v = *(const float4*)(src + idx);
    ushort4 o;
    o.x = f2b(v.x); o.y = f2b(v.y); o.z = f2b(v.z); o.w = f2b(v.w);
    *(ushort4*)(dst + idx) = o;
  }
}

// fused weight conversion: dst = [Wq | Wk | Wv | Wo] contiguous
__global__ void cvt_w4(const float* __restrict__ Wq, const float* __restrict__ Wk,
                       const float* __restrict__ Wv, const float* __restrict__ Wo,
                       u16* __restrict__ dst) {
  const int total = 10485760;
  int stride = gridDim.x * blockDim.x * 4;
  for (int idx = (blockIdx.x * blockDim.x + threadIdx.x) * 4; idx < total; idx += stride) {
    const float* src;
    int off;
    if (idx < 4194304) { src = Wq; off = idx; }
    else if (idx < 5242880) { src = Wk; off = idx - 4194304; }
    else if (idx < 6291456) { src = Wv; off = idx - 5242880; }
    else { src = Wo; off = idx - 6291456; }
    float4 v = *(const float4*)(src + off);
    ushort4 o;
    o.x = f2b(v.x); o.y = f2b(v.y); o.z = f2b(v.z); o.w = f2b(v.w);
    *(ushort4*)(dst + idx) = o;
  }
}

// ---------------- GEMM: C[M,N] = A[M,K] * B[N,K]^T ----------------
// OUT_MODE: 0 = bf16 row-major; 2 = fp32 row-major; 3 = fused QKV routing
template<int OUT_MODE>
__global__ __launch_bounds__(256) void gemm_bt(const u16* __restrict__ A, const u16* __restrict__ B,
                                               void* __restrict__ Cout, int M, int N, int Kd,
                                               u16* __restrict__ Kout, u16* __restrict__ Vtout) {
  __shared__ u16 sA[128 * 32];
  __shared__ u16 sB[128 * 32];
  const int tid = threadIdx.x;
  const int l = tid & 63, w = tid >> 6;
  const int wr = w >> 1, wc = w & 1;
  const int g = l >> 4, c = l & 15;
  const int tm = blockIdx.y * 128, tn = blockIdx.x * 128;

  f32x4 acc[4][4] = {};

  const int r0 = tid >> 2, cc = (tid & 3) << 3;

  for (int k0 = 0; k0 < Kd; k0 += 32) {
    __syncthreads();
    {
      const u16* srcA0 = A + (size_t)(tm + r0) * Kd + k0 + cc;
      const u16* srcB0 = B + (size_t)(tn + r0) * Kd + k0 + cc;
      gload_lds16(srcA0, (char*)sA + w * 1024);
      gload_lds16(srcB0, (char*)sB + w * 1024);
      gload_lds16(srcA0 + (size_t)64 * Kd, (char*)sA + 4096 + w * 1024);
      gload_lds16(srcB0 + (size_t)64 * Kd, (char*)sB + 4096 + w * 1024);
    }
    __syncthreads();

    bf16x8 af[4], bfr[4];
#pragma unroll
    for (int m = 0; m < 4; ++m)
      af[m] = *(const bf16x8*)(sA + (wr * 64 + m * 16 + c) * 32 + g * 8);
#pragma unroll
    for (int n = 0; n < 4; ++n)
      bfr[n] = *(const bf16x8*)(sB + (wc * 64 + n * 16 + c) * 32 + g * 8);
#pragma unroll
    for (int m = 0; m < 4; ++m)
#pragma unroll
      for (int n = 0; n < 4; ++n)
        acc[m][n] = __builtin_amdgcn_mfma_f32_16x16x32_bf16(af[m], bfr[n], acc[m][n], 0, 0, 0);
  }

#pragma unroll
  for (int m = 0; m < 4; ++m)
#pragma unroll
    for (int n = 0; n < 4; ++n)
#pragma unroll
      for (int i = 0; i < 4; ++i) {
        int row = tm + wr * 64 + m * 16 + g * 4 + i;
        int col = tn + wc * 64 + n * 16 + c;
        float v = acc[m][n][i];
        if constexpr (OUT_MODE == 2) {
          ((float*)Cout)[(size_t)row * N + col] = v;
        } else if constexpr (OUT_MODE == 0) {
          ((u16*)Cout)[(size_t)row * N + col] = f2b(v);
        } else {
          if (tn < 2048) {
            ((u16*)Cout)[(size_t)row * 2048 + col] = f2b(v);          // Q
          } else if (tn < 2560) {
            Kout[(size_t)row * 512 + (col - 2048)] = f2b(v);          // K
          } else {
            int bb = row >> 11, s = row & 2047;                        // V^T
            Vtout[((size_t)bb * 512 + (col - 2560)) * 2048 + s] = f2b(v);
          }
        }
      }
}

// ---------------- causal GQA flash attention: 32x32 swapped-operand + intra-block KV-split ----
// grid (32, 32), block 256 (4 waves). tile = 31 - blockIdx.x (longest first).
// Wave w: q-subtile (w&1) [32 rows], kv-half (w>>1): kv tiles kt = kvhalf, kvhalf+2, ...
// Doubles wave-parallelism (4096 waves) vs per-wave full-KV; partials merged via LDS.
__global__ __launch_bounds__(256, 4) void attn_fwd(const u16* __restrict__ Q, const u16* __restrict__ Kt,
                                                   const u16* __restrict__ Vt, u16* __restrict__ AO) {
  const int l = threadIdx.x & 63, w = threadIdx.x >> 6;
  const int ql = l & 31, hi = l >> 5;
  const int bh = blockIdx.y;
  const int b = bh >> 4, h = bh & 15;
  const int kvh = h >> 2;

  __shared__ float4 mO[2][16][64];   // [kv-half-1 waves][elem][lane]
  __shared__ float mML[2][2][64];

  const float sm = 0.08838834764831845f * 1.4426950408889634f;  // 1/sqrt(128) * log2(e)

  const u16* Kb = Kt + (size_t)(b * 2048) * 512 + kvh * 128;
  const u16* Vb = Vt + (size_t)(b * 512 + kvh * 128) * 2048;

  const int tile = 31 - (int)blockIdx.x;
  const int qs = w & 1, kvhalf = w >> 1;
  const int q0 = tile * 64 + qs * 32;

  // Q fragments (B-operand of QK: col=q=lane&31, k = ck*16 + hi*8 + j)
  bf16x8 qf[8];
  {
    const u16* qb = Q + ((size_t)(b * 2048 + q0 + ql)) * 2048 + h * 128 + hi * 8;
#pragma unroll
    for (int ck = 0; ck < 8; ++ck) qf[ck] = *(const bf16x8*)(qb + ck * 16);
  }

  f32x16 acc[4] = {};  // O^T[d = db*32 + crow(r)][q = q0 + (lane&31)]
  float mrow = -1e30f, lrow = 0.f;

  bf16x8 kfa[8], kfb[8];

#define LOADK(KF, KV0)                                                        \
  do {                                                                        \
    const u16* kb_ = Kb + (size_t)((KV0) + ql) * 512 + hi * 8;                \
    _Pragma("unroll") for (int ck = 0; ck < 8; ++ck)                          \
        KF[ck] = *(const bf16x8*)(kb_ + ck * 16);                             \
  } while (0)

#define COMPUTE(KF, KV0)                                                      \
  do {                                                                        \
    bf16x8 vtf[2][4];                                                         \
    {                                                                         \
      const u16* vb_ = Vb + (size_t)ql * 2048 + (KV0) + hi * 8;               \
      _Pragma("unroll") for (int ks = 0; ks < 2; ++ks)                        \
      _Pragma("unroll") for (int db = 0; db < 4; ++db)                        \
          vtf[ks][db] = *(const bf16x8*)(vb_ + (size_t)(db * 32) * 2048 + ks * 16); \
    }                                                                         \
    f32x16 sacc = {};                                                         \
    __builtin_amdgcn_s_setprio(1);                                            \
    _Pragma("unroll") for (int ck = 0; ck < 8; ++ck)                          \
        sacc = __builtin_amdgcn_mfma_f32_32x32x16_bf16(KF[ck], qf[ck], sacc, 0, 0, 0); \
    __builtin_amdgcn_s_setprio(0);                                            \
    if ((KV0) == q0) { /* diagonal: mask kv > q */                            \
      _Pragma("unroll") for (int r = 0; r < 16; ++r) {                        \
        int crow = (r & 3) + 8 * (r >> 2) + 4 * hi;                           \
        if (crow > ql) sacc[r] = -1e30f;                                      \
      }                                                                       \
    }                                                                         \
    float t0 = fmaxf(sacc[0], sacc[1]), t1 = fmaxf(sacc[2], sacc[3]);         \
    float t2 = fmaxf(sacc[4], sacc[5]), t3 = fmaxf(sacc[6], sacc[7]);         \
    float t4 = fmaxf(sacc[8], sacc[9]), t5 = fmaxf(sacc[10], sacc[11]);       \
    float t6 = fmaxf(sacc[12], sacc[13]), t7 = fmaxf(sacc[14], sacc[15]);     \
    float mx = fmaxf(fmaxf(fmaxf(t0, t1), fmaxf(t2, t3)),                     \
                     fmaxf(fmaxf(t4, t5), fmaxf(t6, t7)));                    \
    mx = xhalf_max(mx);                                                       \
    float p[16];                                                              \
    _Pragma("unroll") for (int r = 0; r < 16; ++r)                            \
        p[r] = exp2f((sacc[r] - mrow) * sm);                                  \
    if (!__all((mx - mrow) * sm <= 8.0f)) { /* T13 defer-max */               \
      float mnew = fmaxf(mrow, mx);                                           \
      float rs = exp2f((mrow - mnew) * sm);                                   \
      mrow = mnew;                                                            \
      lrow *= rs;                                                             \
      _Pragma("unroll") for (int db = 0; db < 4; ++db)                        \
      _Pragma("unroll") for (int r = 0; r < 16; ++r) acc[db][r] *= rs;        \
      _Pragma("unroll") for (int r = 0; r < 16; ++r)                          \
          p[r] = exp2f((sacc[r] - mrow) * sm);                                \
    }                                                                         \
    float s0 = p[0] + p[1], s1 = p[2] + p[3], s2 = p[4] + p[5], s3 = p[6] + p[7]; \
    float s4 = p[8] + p[9], s5 = p[10] + p[11], s6 = p[12] + p[13], s7 = p[14] + p[15]; \
    float psum = ((s0 + s1) + (s2 + s3)) + ((s4 + s5) + (s6 + s7));           \
    lrow += xhalf_sum(psum);                                                  \
    u32 a0 = pktrunc(p[0], p[1]), a1 = pktrunc(p[2], p[3]);                   \
    u32 a2 = pktrunc(p[4], p[5]), a3 = pktrunc(p[6], p[7]);                   \
    u32 b0 = pktrunc(p[8], p[9]), b1 = pktrunc(p[10], p[11]);                 \
    u32 b2 = pktrunc(p[12], p[13]), b3 = pktrunc(p[14], p[15]);               \
    union { bf16x8 v; u32 u[4]; } pa0, pa1;                                   \
    xexchange(hi, a0, a1, a2, a3, pa0.u);                                     \
    xexchange(hi, b0, b1, b2, b3, pa1.u);                                     \
    __builtin_amdgcn_s_setprio(1);                                            \
    _Pragma("unroll") for (int db = 0; db < 4; ++db) {                        \
      acc[db] = __builtin_amdgcn_mfma_f32_32x32x16_bf16(vtf[0][db], pa0.v, acc[db], 0, 0, 0); \
      acc[db] = __builtin_amdgcn_mfma_f32_32x32x16_bf16(vtf[1][db], pa1.v, acc[db], 0, 0, 0); \
    }                                                                         \
    __builtin_amdgcn_s_setprio(0);                                            \
  } while (0)

  // kv loop over tiles kt = kvhalf, kvhalf+2, ... while kt*32 <= q0 (K double-buffered)
  int kv0 = kvhalf * 32;
  if (kv0 <= q0) {
    LOADK(kfa, kv0);
    while (true) {
      bool more = kv0 + 64 <= q0;
      if (more) LOADK(kfb, kv0 + 64);
      COMPUTE(kfa, kv0);
      if (!more) break;
      kv0 += 64;
      more = kv0 + 64 <= q0;
      if (more) LOADK(kfa, kv0 + 64);
      COMPUTE(kfb, kv0);
      if (!more) break;
      kv0 += 64;
    }
  }
#undef LOADK
#undef COMPUTE

  // ---- merge kv-halves: waves 2,3 publish partials; waves 0,1 combine + store ----
  if (w >= 2) {
    const int wi = w - 2;
#pragma unroll
    for (int db = 0; db < 4; ++db)
#pragma unroll
      for (int rq = 0; rq < 4; ++rq) {
        float4 v;
        v.x = acc[db][rq * 4 + 0];
        v.y = acc[db][rq * 4 + 1];
        v.z = acc[db][rq * 4 + 2];
        v.w = acc[db][rq * 4 + 3];
        mO[wi][db * 4 + rq][l] = v;
      }
    mML[wi][0][l] = mrow;
    mML[wi][1][l] = lrow;
  }
  __syncthreads();
  if (w < 2) {
    float m1 = mML[w][0][l], l1 = mML[w][1][l];
    float mnew = fmaxf(mrow, m1);
    float s0 = exp2f((mrow - mnew) * sm);
    float s1 = exp2f((m1 - mnew) * sm);
    float inv = 1.0f / (lrow * s0 + l1 * s1);
    float f0 = s0 * inv, f1 = s1 * inv;
    u16* ob = AO + (size_t)(b * 2048 + q0 + ql) * 2048 + h * 128 + hi * 4;
#pragma unroll
    for (int db = 0; db < 4; ++db)
#pragma unroll
      for (int rq = 0; rq < 4; ++rq) {
        float4 o1 = mO[w][db * 4 + rq][l];
        ushort4 o;
        o.x = f2b(acc[db][rq * 4 + 0] * f0 + o1.x * f1);
        o.y = f2b(acc[db][rq * 4 + 1] * f0 + o1.y * f1);
        o.z = f2b(acc[db][rq * 4 + 2] * f0 + o1.z * f1);
        o.w = f2b(acc[db][rq * 4 + 3] * f0 + o1.w * f1);
        *(ushort4*)(ob + db * 32 + rq * 8) = o;
      }
  }
}

// ---------------- host ----------------
extern "C" void kernel_launch(void* const* d_in, const int* in_sizes, int n_in,
                              void* d_out, int out_size, void* d_ws, size_t ws_size,
                              hipStream_t stream) {
  const float* X = (const float*)d_in[0];
  const float* Wq = (const float*)d_in[1];
  const float* Wk = (const float*)d_in[2];
  const float* Wv = (const float*)d_in[3];
  const float* Wo = (const float*)d_in[4];

  u16* ws = (u16*)d_ws;
  const size_t nX = 8388608;   // 2*2048*2048
  const size_t nWq = 4194304;  // 2048*2048
  const size_t nWk = 1048576;  // 512*2048
  u16* Xb = ws;
  u16* Wqb = Xb + nX;          // [Wq|Wk|Wv] contiguous = fused 3072x2048 weight
  u16* Wkb = Wqb + nWq;
  u16* Wvb = Wkb + nWk;
  u16* Wob = Wvb + nWk;
  u16* Qb = Wob + nWq;
  u16* Kb = Qb + nX;
  u16* Vtb = Kb + 2097152;
  u16* AOb = Vtb + 2097152;
  if (ws_size < (size_t)(39845888) * 2) return;

  cvt_bf16<<<2048, 256, 0, stream>>>(X, Xb, (int)nX);
  cvt_w4<<<2048, 256, 0, stream>>>(Wq, Wk, Wv, Wo, Wqb);

  // fused QKV projection: C[4096][3072] routed to Q / K / V^T
  gemm_bt<3><<<dim3(24, 32), 256, 0, stream>>>(Xb, Wqb, Qb, 4096, 3072, 2048, Kb, Vtb);

  attn_fwd<<<dim3(32, 32), 256, 0, stream>>>(Qb, Kb, Vtb, AOb);

  // output projection -> fp32 d_out
  gemm_bt<2><<<dim3(16, 32), 256, 0, stream>>>(AOb, Wob, d_out, 4096, 2048, 2048, nullptr, nullptr);
}

// Round 9
// 378.925 us; speedup vs baseline: 2.0408x; 2.0408x over previous
//
#include <hip/hip_runtime.h>

typedef unsigned short u16;
typedef unsigned int u32;
typedef __attribute__((ext_vector_type(4))) float f32x4;
typedef __attribute__((ext_vector_type(16))) float f32x16;
typedef __attribute__((ext_vector_type(8))) short bf16x8;

// Problem sizes (fixed): B=2, S=2048, D=2048, NH=16, NKV=4, HD=128

__device__ __forceinline__ u16 f2b(float f) {
  u32 u = __builtin_bit_cast(u32, f);
  u = (u + 0x7fffu + ((u >> 16) & 1u)) >> 16;  // RNE
  return (u16)u;
}

__device__ __forceinline__ void gload_lds16(const void* g, void* l) {
  __builtin_amdgcn_global_load_lds((const __attribute__((address_space(1))) u32*)g,
                                   (__attribute__((address_space(3))) u32*)l, 16, 0, 0);
}

// ---- cross-half (lane <-> lane^32) exchange via v_permlane32_swap_b32 (VALU pipe) ----
#if __has_builtin(__builtin_amdgcn_permlane32_swap)
#define HAS_PLS 1
__device__ __forceinline__ void pls(u32 x, u32 y, u32& rx, u32& ry) {
  auto r = __builtin_amdgcn_permlane32_swap(x, y, false, false);
  rx = (u32)r[0];
  ry = (u32)r[1];
}
#endif

__device__ __forceinline__ float xhalf_max(float v) {
#ifdef HAS_PLS
  u32 a, b;
  pls(__builtin_bit_cast(u32, v), __builtin_bit_cast(u32, v), a, b);
  return fmaxf(__builtin_bit_cast(float, a), __builtin_bit_cast(float, b));
#else
  return fmaxf(v, __shfl_xor(v, 32));
#endif
}

__device__ __forceinline__ float xhalf_sum(float v) {
#ifdef HAS_PLS
  u32 a, b;
  pls(__builtin_bit_cast(u32, v), __builtin_bit_cast(u32, v), a, b);
  return __builtin_bit_cast(float, a) + __builtin_bit_cast(float, b);
#else
  return v + __shfl_xor(v, 32);
#endif
}

// P-fragment redistribution across lane halves
__device__ __forceinline__ void xexchange(int hi, u32 a0, u32 a1, u32 a2, u32 a3, u32* o) {
#ifdef HAS_PLS
  pls(a0, a2, o[0], o[2]);
  pls(a1, a3, o[1], o[3]);
#else
  u32 xa0 = (u32)__shfl_xor((int)a0, 32), xa1 = (u32)__shfl_xor((int)a1, 32);
  u32 xa2 = (u32)__shfl_xor((int)a2, 32), xa3 = (u32)__shfl_xor((int)a3, 32);
  o[0] = hi ? xa2 : a0;
  o[1] = hi ? xa3 : a1;
  o[2] = hi ? a2 : xa0;
  o[3] = hi ? a3 : xa1;
#endif
}

// truncating bf16 pair pack (P in [0,1]; <=2^-8 rel err, cheap: 3 ops)
__device__ __forceinline__ u32 pktrunc(float lo, float hif) {
  return (__builtin_bit_cast(u32, lo) >> 16) | (__builtin_bit_cast(u32, hif) & 0xffff0000u);
}

// ---------------- fp32 -> bf16 conversion ----------------
__global__ void cvt_bf16(const float* __restrict__ src, u16* __restrict__ dst, int n) {
  int stride = gridDim.x * blockDim.x * 4;
  for (int idx = (blockIdx.x * blockDim.x + threadIdx.x) * 4; idx < n; idx += stride) {
    float4 v = *(const float4*)(src + idx);
    ushort4 o;
    o.x = f2b(v.x); o.y = f2b(v.y); o.z = f2b(v.z); o.w = f2b(v.w);
    *(ushort4*)(dst + idx) = o;
  }
}

// fused weight conversion: dst = [Wq | Wk | Wv | Wo] contiguous
__global__ void cvt_w4(const float* __restrict__ Wq, const float* __restrict__ Wk,
                       const float* __restrict__ Wv, const float* __restrict__ Wo,
                       u16* __restrict__ dst) {
  const int total = 10485760;
  int stride = gridDim.x * blockDim.x * 4;
  for (int idx = (blockIdx.x * blockDim.x + threadIdx.x) * 4; idx < total; idx += stride) {
    const float* src;
    int off;
    if (idx < 4194304) { src = Wq; off = idx; }
    else if (idx < 5242880) { src = Wk; off = idx - 4194304; }
    else if (idx < 6291456) { src = Wv; off = idx - 5242880; }
    else { src = Wo; off = idx - 6291456; }
    float4 v = *(const float4*)(src + off);
    ushort4 o;
    o.x = f2b(v.x); o.y = f2b(v.y); o.z = f2b(v.z); o.w = f2b(v.w);
    *(ushort4*)(dst + idx) = o;
  }
}

// ---------------- GEMM: C[M,N] = A[M,K] * B[N,K]^T ----------------
// OUT_MODE: 0 = bf16 row-major; 2 = fp32 row-major; 3 = fused QKV routing
template<int OUT_MODE>
__global__ __launch_bounds__(256) void gemm_bt(const u16* __restrict__ A, const u16* __restrict__ B,
                                               void* __restrict__ Cout, int M, int N, int Kd,
                                               u16* __restrict__ Kout, u16* __restrict__ Vtout) {
  __shared__ u16 sA[128 * 32];
  __shared__ u16 sB[128 * 32];
  const int tid = threadIdx.x;
  const int l = tid & 63, w = tid >> 6;
  const int wr = w >> 1, wc = w & 1;
  const int g = l >> 4, c = l & 15;
  const int tm = blockIdx.y * 128, tn = blockIdx.x * 128;

  f32x4 acc[4][4] = {};

  const int r0 = tid >> 2, cc = (tid & 3) << 3;

  for (int k0 = 0; k0 < Kd; k0 += 32) {
    __syncthreads();
    {
      const u16* srcA0 = A + (size_t)(tm + r0) * Kd + k0 + cc;
      const u16* srcB0 = B + (size_t)(tn + r0) * Kd + k0 + cc;
      gload_lds16(srcA0, (char*)sA + w * 1024);
      gload_lds16(srcB0, (char*)sB + w * 1024);
      gload_lds16(srcA0 + (size_t)64 * Kd, (char*)sA + 4096 + w * 1024);
      gload_lds16(srcB0 + (size_t)64 * Kd, (char*)sB + 4096 + w * 1024);
    }
    __syncthreads();

    bf16x8 af[4], bfr[4];
#pragma unroll
    for (int m = 0; m < 4; ++m)
      af[m] = *(const bf16x8*)(sA + (wr * 64 + m * 16 + c) * 32 + g * 8);
#pragma unroll
    for (int n = 0; n < 4; ++n)
      bfr[n] = *(const bf16x8*)(sB + (wc * 64 + n * 16 + c) * 32 + g * 8);
#pragma unroll
    for (int m = 0; m < 4; ++m)
#pragma unroll
      for (int n = 0; n < 4; ++n)
        acc[m][n] = __builtin_amdgcn_mfma_f32_16x16x32_bf16(af[m], bfr[n], acc[m][n], 0, 0, 0);
  }

#pragma unroll
  for (int m = 0; m < 4; ++m)
#pragma unroll
    for (int n = 0; n < 4; ++n)
#pragma unroll
      for (int i = 0; i < 4; ++i) {
        int row = tm + wr * 64 + m * 16 + g * 4 + i;
        int col = tn + wc * 64 + n * 16 + c;
        float v = acc[m][n][i];
        if constexpr (OUT_MODE == 2) {
          ((float*)Cout)[(size_t)row * N + col] = v;
        } else if constexpr (OUT_MODE == 0) {
          ((u16*)Cout)[(size_t)row * N + col] = f2b(v);
        } else {
          if (tn < 2048) {
            ((u16*)Cout)[(size_t)row * 2048 + col] = f2b(v);          // Q
          } else if (tn < 2560) {
            Kout[(size_t)row * 512 + (col - 2048)] = f2b(v);          // K
          } else {
            int bb = row >> 11, s = row & 2047;                        // V^T
            Vtout[((size_t)bb * 512 + (col - 2560)) * 2048 + s] = f2b(v);
          }
        }
      }
}

// ---------------- causal GQA flash attention: 32x32 swapped-operand + intra-block KV-split ----
// grid (32, 32), block 256 (4 waves). tile = 31 - blockIdx.x (longest first).
// Wave w: q-subtile (w&1) [32 rows], kv-half (w>>1): kv tiles kt = kvhalf, kvhalf+2, ...
// NOTE: min-waves arg MUST be 2 — (256,4) caps VGPR at 64 and spills everything to scratch
// (round 8: 1.5 GB HBM traffic/dispatch, 5x regression).
__global__ __launch_bounds__(256, 2) void attn_fwd(const u16* __restrict__ Q, const u16* __restrict__ Kt,
                                                   const u16* __restrict__ Vt, u16* __restrict__ AO) {
  const int l = threadIdx.x & 63, w = threadIdx.x >> 6;
  const int ql = l & 31, hi = l >> 5;
  const int bh = blockIdx.y;
  const int b = bh >> 4, h = bh & 15;
  const int kvh = h >> 2;

  __shared__ float4 mO[2][16][64];   // [kv-half-1 waves][elem][lane]
  __shared__ float mML[2][2][64];

  const float sm = 0.08838834764831845f * 1.4426950408889634f;  // 1/sqrt(128) * log2(e)

  const u16* Kb = Kt + (size_t)(b * 2048) * 512 + kvh * 128;
  const u16* Vb = Vt + (size_t)(b * 512 + kvh * 128) * 2048;

  const int tile = 31 - (int)blockIdx.x;
  const int qs = w & 1, kvhalf = w >> 1;
  const int q0 = tile * 64 + qs * 32;

  // Q fragments (B-operand of QK: col=q=lane&31, k = ck*16 + hi*8 + j)
  bf16x8 qf[8];
  {
    const u16* qb = Q + ((size_t)(b * 2048 + q0 + ql)) * 2048 + h * 128 + hi * 8;
#pragma unroll
    for (int ck = 0; ck < 8; ++ck) qf[ck] = *(const bf16x8*)(qb + ck * 16);
  }

  f32x16 acc[4] = {};  // O^T[d = db*32 + crow(r)][q = q0 + (lane&31)]
  float mrow = -1e30f, lrow = 0.f;

  bf16x8 kfa[8], kfb[8];

#define LOADK(KF, KV0)                                                        \
  do {                                                                        \
    const u16* kb_ = Kb + (size_t)((KV0) + ql) * 512 + hi * 8;                \
    _Pragma("unroll") for (int ck = 0; ck < 8; ++ck)                          \
        KF[ck] = *(const bf16x8*)(kb_ + ck * 16);                             \
  } while (0)

#define COMPUTE(KF, KV0)                                                      \
  do {                                                                        \
    bf16x8 vtf[2][4];                                                         \
    {                                                                         \
      const u16* vb_ = Vb + (size_t)ql * 2048 + (KV0) + hi * 8;               \
      _Pragma("unroll") for (int ks = 0; ks < 2; ++ks)                        \
      _Pragma("unroll") for (int db = 0; db < 4; ++db)                        \
          vtf[ks][db] = *(const bf16x8*)(vb_ + (size_t)(db * 32) * 2048 + ks * 16); \
    }                                                                         \
    f32x16 sacc = {};                                                         \
    __builtin_amdgcn_s_setprio(1);                                            \
    _Pragma("unroll") for (int ck = 0; ck < 8; ++ck)                          \
        sacc = __builtin_amdgcn_mfma_f32_32x32x16_bf16(KF[ck], qf[ck], sacc, 0, 0, 0); \
    __builtin_amdgcn_s_setprio(0);                                            \
    if ((KV0) == q0) { /* diagonal: mask kv > q */                            \
      _Pragma("unroll") for (int r = 0; r < 16; ++r) {                        \
        int crow = (r & 3) + 8 * (r >> 2) + 4 * hi;                           \
        if (crow > ql) sacc[r] = -1e30f;                                      \
      }                                                                       \
    }                                                                         \
    float t0 = fmaxf(sacc[0], sacc[1]), t1 = fmaxf(sacc[2], sacc[3]);         \
    float t2 = fmaxf(sacc[4], sacc[5]), t3 = fmaxf(sacc[6], sacc[7]);         \
    float t4 = fmaxf(sacc[8], sacc[9]), t5 = fmaxf(sacc[10], sacc[11]);       \
    float t6 = fmaxf(sacc[12], sacc[13]), t7 = fmaxf(sacc[14], sacc[15]);     \
    float mx = fmaxf(fmaxf(fmaxf(t0, t1), fmaxf(t2, t3)),                     \
                     fmaxf(fmaxf(t4, t5), fmaxf(t6, t7)));                    \
    mx = xhalf_max(mx);                                                       \
    float p[16];                                                              \
    _Pragma("unroll") for (int r = 0; r < 16; ++r)                            \
        p[r] = exp2f((sacc[r] - mrow) * sm);                                  \
    if (!__all((mx - mrow) * sm <= 8.0f)) { /* T13 defer-max */               \
      float mnew = fmaxf(mrow, mx);                                           \
      float rs = exp2f((mrow - mnew) * sm);                                   \
      mrow = mnew;                                                            \
      lrow *= rs;                                                             \
      _Pragma("unroll") for (int db = 0; db < 4; ++db)                        \
      _Pragma("unroll") for (int r = 0; r < 16; ++r) acc[db][r] *= rs;        \
      _Pragma("unroll") for (int r = 0; r < 16; ++r)                          \
          p[r] = exp2f((sacc[r] - mrow) * sm);                                \
    }                                                                         \
    float s0 = p[0] + p[1], s1 = p[2] + p[3], s2 = p[4] + p[5], s3 = p[6] + p[7]; \
    float s4 = p[8] + p[9], s5 = p[10] + p[11], s6 = p[12] + p[13], s7 = p[14] + p[15]; \
    float psum = ((s0 + s1) + (s2 + s3)) + ((s4 + s5) + (s6 + s7));           \
    lrow += xhalf_sum(psum);                                                  \
    u32 a0 = pktrunc(p[0], p[1]), a1 = pktrunc(p[2], p[3]);                   \
    u32 a2 = pktrunc(p[4], p[5]), a3 = pktrunc(p[6], p[7]);                   \
    u32 b0 = pktrunc(p[8], p[9]), b1 = pktrunc(p[10], p[11]);                 \
    u32 b2 = pktrunc(p[12], p[13]), b3 = pktrunc(p[14], p[15]);               \
    union { bf16x8 v; u32 u[4]; } pa0, pa1;                                   \
    xexchange(hi, a0, a1, a2, a3, pa0.u);                                     \
    xexchange(hi, b0, b1, b2, b3, pa1.u);                                     \
    __builtin_amdgcn_s_setprio(1);                                            \
    _Pragma("unroll") for (int db = 0; db < 4; ++db) {                        \
      acc[db] = __builtin_amdgcn_mfma_f32_32x32x16_bf16(vtf[0][db], pa0.v, acc[db], 0, 0, 0); \
      acc[db] = __builtin_amdgcn_mfma_f32_32x32x16_bf16(vtf[1][db], pa1.v, acc[db], 0, 0, 0); \
    }                                                                         \
    __builtin_amdgcn_s_setprio(0);                                            \
  } while (0)

  // kv loop over tiles kt = kvhalf, kvhalf+2, ... while kt*32 <= q0 (K double-buffered)
  int kv0 = kvhalf * 32;
  if (kv0 <= q0) {
    LOADK(kfa, kv0);
    while (true) {
      bool more = kv0 + 64 <= q0;
      if (more) LOADK(kfb, kv0 + 64);
      COMPUTE(kfa, kv0);
      if (!more) break;
      kv0 += 64;
      more = kv0 + 64 <= q0;
      if (more) LOADK(kfa, kv0 + 64);
      COMPUTE(kfb, kv0);
      if (!more) break;
      kv0 += 64;
    }
  }
#undef LOADK
#undef COMPUTE

  // ---- merge kv-halves: waves 2,3 publish partials; waves 0,1 combine + store ----
  if (w >= 2) {
    const int wi = w - 2;
#pragma unroll
    for (int db = 0; db < 4; ++db)
#pragma unroll
      for (int rq = 0; rq < 4; ++rq) {
        float4 v;
        v.x = acc[db][rq * 4 + 0];
        v.y = acc[db][rq * 4 + 1];
        v.z = acc[db][rq * 4 + 2];
        v.w = acc[db][rq * 4 + 3];
        mO[wi][db * 4 + rq][l] = v;
      }
    mML[wi][0][l] = mrow;
    mML[wi][1][l] = lrow;
  }
  __syncthreads();
  if (w < 2) {
    float m1 = mML[w][0][l], l1 = mML[w][1][l];
    float mnew = fmaxf(mrow, m1);
    float s0 = exp2f((mrow - mnew) * sm);
    float s1 = exp2f((m1 - mnew) * sm);
    float inv = 1.0f / (lrow * s0 + l1 * s1);
    float f0 = s0 * inv, f1 = s1 * inv;
    u16* ob = AO + (size_t)(b * 2048 + q0 + ql) * 2048 + h * 128 + hi * 4;
#pragma unroll
    for (int db = 0; db < 4; ++db)
#pragma unroll
      for (int rq = 0; rq < 4; ++rq) {
        float4 o1 = mO[w][db * 4 + rq][l];
        ushort4 o;
        o.x = f2b(acc[db][rq * 4 + 0] * f0 + o1.x * f1);
        o.y = f2b(acc[db][rq * 4 + 1] * f0 + o1.y * f1);
        o.z = f2b(acc[db][rq * 4 + 2] * f0 + o1.z * f1);
        o.w = f2b(acc[db][rq * 4 + 3] * f0 + o1.w * f1);
        *(ushort4*)(ob + db * 32 + rq * 8) = o;
      }
  }
}

// ---------------- host ----------------
extern "C" void kernel_launch(void* const* d_in, const int* in_sizes, int n_in,
                              void* d_out, int out_size, void* d_ws, size_t ws_size,
                              hipStream_t stream) {
  const float* X = (const float*)d_in[0];
  const float* Wq = (const float*)d_in[1];
  const float* Wk = (const float*)d_in[2];
  const float* Wv = (const float*)d_in[3];
  const float* Wo = (const float*)d_in[4];

  u16* ws = (u16*)d_ws;
  const size_t nX = 8388608;   // 2*2048*2048
  const size_t nWq = 4194304;  // 2048*2048
  const size_t nWk = 1048576;  // 512*2048
  u16* Xb = ws;
  u16* Wqb = Xb + nX;          // [Wq|Wk|Wv] contiguous = fused 3072x2048 weight
  u16* Wkb = Wqb + nWq;
  u16* Wvb = Wkb + nWk;
  u16* Wob = Wvb + nWk;
  u16* Qb = Wob + nWq;
  u16* Kb = Qb + nX;
  u16* Vtb = Kb + 2097152;
  u16* AOb = Vtb + 2097152;
  if (ws_size < (size_t)(39845888) * 2) return;

  cvt_bf16<<<2048, 256, 0, stream>>>(X, Xb, (int)nX);
  cvt_w4<<<2048, 256, 0, stream>>>(Wq, Wk, Wv, Wo, Wqb);

  // fused QKV projection: C[4096][3072] routed to Q / K / V^T
  gemm_bt<3><<<dim3(24, 32), 256, 0, stream>>>(Xb, Wqb, Qb, 4096, 3072, 2048, Kb, Vtb);

  attn_fwd<<<dim3(32, 32), 256, 0, stream>>>(Qb, Kb, Vtb, AOb);

  // output projection -> fp32 d_out
  gemm_bt<2><<<dim3(16, 32), 256, 0, stream>>>(AOb, Wob, d_out, 4096, 2048, 2048, nullptr, nullptr);
}

// Round 10
// 275.779 us; speedup vs baseline: 2.8041x; 1.3740x over previous
//
#include <hip/hip_runtime.h>

typedef unsigned short u16;
typedef unsigned int u32;
typedef __attribute__((ext_vector_type(4))) float f32x4;
typedef __attribute__((ext_vector_type(16))) float f32x16;
typedef __attribute__((ext_vector_type(8))) short bf16x8;

// Problem sizes (fixed): B=2, S=2048, D=2048, NH=16, NKV=4, HD=128

__device__ __forceinline__ u16 f2b(float f) {
  u32 u = __builtin_bit_cast(u32, f);
  u = (u + 0x7fffu + ((u >> 16) & 1u)) >> 16;  // RNE
  return (u16)u;
}

__device__ __forceinline__ void gload_lds16(const void* g, void* l) {
  __builtin_amdgcn_global_load_lds((const __attribute__((address_space(1))) u32*)g,
                                   (__attribute__((address_space(3))) u32*)l, 16, 0, 0);
}

// ---- cross-half (lane <-> lane^32) exchange via v_permlane32_swap_b32 (VALU pipe) ----
#if __has_builtin(__builtin_amdgcn_permlane32_swap)
#define HAS_PLS 1
__device__ __forceinline__ void pls(u32 x, u32 y, u32& rx, u32& ry) {
  auto r = __builtin_amdgcn_permlane32_swap(x, y, false, false);
  rx = (u32)r[0];
  ry = (u32)r[1];
}
#endif

__device__ __forceinline__ float xhalf_max(float v) {
#ifdef HAS_PLS
  u32 a, b;
  pls(__builtin_bit_cast(u32, v), __builtin_bit_cast(u32, v), a, b);
  return fmaxf(__builtin_bit_cast(float, a), __builtin_bit_cast(float, b));
#else
  return fmaxf(v, __shfl_xor(v, 32));
#endif
}

__device__ __forceinline__ float xhalf_sum(float v) {
#ifdef HAS_PLS
  u32 a, b;
  pls(__builtin_bit_cast(u32, v), __builtin_bit_cast(u32, v), a, b);
  return __builtin_bit_cast(float, a) + __builtin_bit_cast(float, b);
#else
  return v + __shfl_xor(v, 32);
#endif
}

// P-fragment redistribution across lane halves
__device__ __forceinline__ void xexchange(int hi, u32 a0, u32 a1, u32 a2, u32 a3, u32* o) {
#ifdef HAS_PLS
  pls(a0, a2, o[0], o[2]);
  pls(a1, a3, o[1], o[3]);
#else
  u32 xa0 = (u32)__shfl_xor((int)a0, 32), xa1 = (u32)__shfl_xor((int)a1, 32);
  u32 xa2 = (u32)__shfl_xor((int)a2, 32), xa3 = (u32)__shfl_xor((int)a3, 32);
  o[0] = hi ? xa2 : a0;
  o[1] = hi ? xa3 : a1;
  o[2] = hi ? a2 : xa0;
  o[3] = hi ? a3 : xa1;
#endif
}

// truncating bf16 pair pack (P in [0,1]; <=2^-8 rel err, cheap: 3 ops)
__device__ __forceinline__ u32 pktrunc(float lo, float hif) {
  return (__builtin_bit_cast(u32, lo) >> 16) | (__builtin_bit_cast(u32, hif) & 0xffff0000u);
}

// ---------------- fp32 -> bf16 conversion ----------------
__global__ void cvt_bf16(const float* __restrict__ src, u16* __restrict__ dst, int n) {
  int stride = gridDim.x * blockDim.x * 4;
  for (int idx = (blockIdx.x * blockDim.x + threadIdx.x) * 4; idx < n; idx += stride) {
    float4 v = *(const float4*)(src + idx);
    ushort4 o;
    o.x = f2b(v.x); o.y = f2b(v.y); o.z = f2b(v.z); o.w = f2b(v.w);
    *(ushort4*)(dst + idx) = o;
  }
}

// fused weight conversion: dst = [Wq | Wk | Wv | Wo] contiguous
__global__ void cvt_w4(const float* __restrict__ Wq, const float* __restrict__ Wk,
                       const float* __restrict__ Wv, const float* __restrict__ Wo,
                       u16* __restrict__ dst) {
  const int total = 10485760;
  int stride = gridDim.x * blockDim.x * 4;
  for (int idx = (blockIdx.x * blockDim.x + threadIdx.x) * 4; idx < total; idx += stride) {
    const float* src;
    int off;
    if (idx < 4194304) { src = Wq; off = idx; }
    else if (idx < 5242880) { src = Wk; off = idx - 4194304; }
    else if (idx < 6291456) { src = Wv; off = idx - 5242880; }
    else { src = Wo; off = idx - 6291456; }
    float4 v = *(const float4*)(src + off);
    ushort4 o;
    o.x = f2b(v.x); o.y = f2b(v.y); o.z = f2b(v.z); o.w = f2b(v.w);
    *(ushort4*)(dst + idx) = o;
  }
}

// ---------------- GEMM: C[M,N] = A[M,K] * B[N,K]^T ----------------
// OUT_MODE: 0 = bf16 row-major; 2 = fp32 row-major; 3 = fused QKV routing
template<int OUT_MODE>
__global__ __launch_bounds__(256) void gemm_bt(const u16* __restrict__ A, const u16* __restrict__ B,
                                               void* __restrict__ Cout, int M, int N, int Kd,
                                               u16* __restrict__ Kout, u16* __restrict__ Vtout) {
  __shared__ u16 sA[128 * 32];
  __shared__ u16 sB[128 * 32];
  const int tid = threadIdx.x;
  const int l = tid & 63, w = tid >> 6;
  const int wr = w >> 1, wc = w & 1;
  const int g = l >> 4, c = l & 15;
  const int tm = blockIdx.y * 128, tn = blockIdx.x * 128;

  f32x4 acc[4][4] = {};

  const int r0 = tid >> 2, cc = (tid & 3) << 3;

  for (int k0 = 0; k0 < Kd; k0 += 32) {
    __syncthreads();
    {
      const u16* srcA0 = A + (size_t)(tm + r0) * Kd + k0 + cc;
      const u16* srcB0 = B + (size_t)(tn + r0) * Kd + k0 + cc;
      gload_lds16(srcA0, (char*)sA + w * 1024);
      gload_lds16(srcB0, (char*)sB + w * 1024);
      gload_lds16(srcA0 + (size_t)64 * Kd, (char*)sA + 4096 + w * 1024);
      gload_lds16(srcB0 + (size_t)64 * Kd, (char*)sB + 4096 + w * 1024);
    }
    __syncthreads();

    bf16x8 af[4], bfr[4];
#pragma unroll
    for (int m = 0; m < 4; ++m)
      af[m] = *(const bf16x8*)(sA + (wr * 64 + m * 16 + c) * 32 + g * 8);
#pragma unroll
    for (int n = 0; n < 4; ++n)
      bfr[n] = *(const bf16x8*)(sB + (wc * 64 + n * 16 + c) * 32 + g * 8);
#pragma unroll
    for (int m = 0; m < 4; ++m)
#pragma unroll
      for (int n = 0; n < 4; ++n)
        acc[m][n] = __builtin_amdgcn_mfma_f32_16x16x32_bf16(af[m], bfr[n], acc[m][n], 0, 0, 0);
  }

#pragma unroll
  for (int m = 0; m < 4; ++m)
#pragma unroll
    for (int n = 0; n < 4; ++n)
#pragma unroll
      for (int i = 0; i < 4; ++i) {
        int row = tm + wr * 64 + m * 16 + g * 4 + i;
        int col = tn + wc * 64 + n * 16 + c;
        float v = acc[m][n][i];
        if constexpr (OUT_MODE == 2) {
          ((float*)Cout)[(size_t)row * N + col] = v;
        } else if constexpr (OUT_MODE == 0) {
          ((u16*)Cout)[(size_t)row * N + col] = f2b(v);
        } else {
          if (tn < 2048) {
            ((u16*)Cout)[(size_t)row * 2048 + col] = f2b(v);          // Q
          } else if (tn < 2560) {
            Kout[(size_t)row * 512 + (col - 2048)] = f2b(v);          // K
          } else {
            int bb = row >> 11, s = row & 2047;                        // V^T
            Vtout[((size_t)bb * 512 + (col - 2560)) * 2048 + s] = f2b(v);
          }
        }
      }
}

// ---------------- causal GQA flash attention: 32x32 swapped-operand + balanced KV-split ----
// grid (32, 32), block 256 (4 waves). Wave w = (ti = w&1, kvhalf = w>>1).
// 32-row q-subtile t = ti ? 63-x : x  -> paired so EVERY block does exactly 65 kv-tile units
// (subtile t needs t+1 kv-tiles; (x+1) + (64-x) = 65). kvhalf strides kv-tiles by 2.
// 1024 equal-work blocks x 4 waves = 4096 waves, all retiring together (occupancy-flat).
// NOTE: min-waves arg MUST be 2 — (256,4) caps VGPR at 64 and spills (round 8: 5x regression).
__global__ __launch_bounds__(256, 2) void attn_fwd(const u16* __restrict__ Q, const u16* __restrict__ Kt,
                                                   const u16* __restrict__ Vt, u16* __restrict__ AO) {
  const int l = threadIdx.x & 63, w = threadIdx.x >> 6;
  const int ql = l & 31, hi = l >> 5;
  const int bh = blockIdx.y;
  const int b = bh >> 4, h = bh & 15;
  const int kvh = h >> 2;

  __shared__ float4 mO[2][16][64];   // [ti][elem][lane] — partials from kvhalf=1 waves
  __shared__ float mML[2][2][64];

  const float sm = 0.08838834764831845f * 1.4426950408889634f;  // 1/sqrt(128) * log2(e)

  const u16* Kb = Kt + (size_t)(b * 2048) * 512 + kvh * 128;
  const u16* Vb = Vt + (size_t)(b * 512 + kvh * 128) * 2048;

  const int ti = w & 1, kvhalf = w >> 1;
  const int t = ti ? (63 - (int)blockIdx.x) : (int)blockIdx.x;
  const int q0 = t * 32;

  // Q fragments (B-operand of QK: col=q=lane&31, k = ck*16 + hi*8 + j)
  bf16x8 qf[8];
  {
    const u16* qb = Q + ((size_t)(b * 2048 + q0 + ql)) * 2048 + h * 128 + hi * 8;
#pragma unroll
    for (int ck = 0; ck < 8; ++ck) qf[ck] = *(const bf16x8*)(qb + ck * 16);
  }

  f32x16 acc[4] = {};  // O^T[d = db*32 + crow(r)][q = q0 + (lane&31)]
  float mrow = -1e30f, lrow = 0.f;

  bf16x8 kfa[8], kfb[8];

#define LOADK(KF, KV0)                                                        \
  do {                                                                        \
    const u16* kb_ = Kb + (size_t)((KV0) + ql) * 512 + hi * 8;                \
    _Pragma("unroll") for (int ck = 0; ck < 8; ++ck)                          \
        KF[ck] = *(const bf16x8*)(kb_ + ck * 16);                             \
  } while (0)

#define COMPUTE(KF, KV0)                                                      \
  do {                                                                        \
    bf16x8 vtf[2][4];                                                         \
    {                                                                         \
      const u16* vb_ = Vb + (size_t)ql * 2048 + (KV0) + hi * 8;               \
      _Pragma("unroll") for (int ks = 0; ks < 2; ++ks)                        \
      _Pragma("unroll") for (int db = 0; db < 4; ++db)                        \
          vtf[ks][db] = *(const bf16x8*)(vb_ + (size_t)(db * 32) * 2048 + ks * 16); \
    }                                                                         \
    f32x16 sacc = {};                                                         \
    __builtin_amdgcn_s_setprio(1);                                            \
    _Pragma("unroll") for (int ck = 0; ck < 8; ++ck)                          \
        sacc = __builtin_amdgcn_mfma_f32_32x32x16_bf16(KF[ck], qf[ck], sacc, 0, 0, 0); \
    __builtin_amdgcn_s_setprio(0);                                            \
    if ((KV0) == q0) { /* diagonal: mask kv > q */                            \
      _Pragma("unroll") for (int r = 0; r < 16; ++r) {                        \
        int crow = (r & 3) + 8 * (r >> 2) + 4 * hi;                           \
        if (crow > ql) sacc[r] = -1e30f;                                      \
      }                                                                       \
    }                                                                         \
    float t0 = fmaxf(sacc[0], sacc[1]), t1 = fmaxf(sacc[2], sacc[3]);         \
    float t2 = fmaxf(sacc[4], sacc[5]), t3 = fmaxf(sacc[6], sacc[7]);         \
    float t4 = fmaxf(sacc[8], sacc[9]), t5 = fmaxf(sacc[10], sacc[11]);       \
    float t6 = fmaxf(sacc[12], sacc[13]), t7 = fmaxf(sacc[14], sacc[15]);     \
    float mx = fmaxf(fmaxf(fmaxf(t0, t1), fmaxf(t2, t3)),                     \
                     fmaxf(fmaxf(t4, t5), fmaxf(t6, t7)));                    \
    mx = xhalf_max(mx);                                                       \
    float p[16];                                                              \
    _Pragma("unroll") for (int r = 0; r < 16; ++r)                            \
        p[r] = exp2f((sacc[r] - mrow) * sm);                                  \
    if (!__all((mx - mrow) * sm <= 8.0f)) { /* T13 defer-max */               \
      float mnew = fmaxf(mrow, mx);                                           \
      float rs = exp2f((mrow - mnew) * sm);                                   \
      mrow = mnew;                                                            \
      lrow *= rs;                                                             \
      _Pragma("unroll") for (int db = 0; db < 4; ++db)                        \
      _Pragma("unroll") for (int r = 0; r < 16; ++r) acc[db][r] *= rs;        \
      _Pragma("unroll") for (int r = 0; r < 16; ++r)                          \
          p[r] = exp2f((sacc[r] - mrow) * sm);                                \
    }                                                                         \
    float s0 = p[0] + p[1], s1 = p[2] + p[3], s2 = p[4] + p[5], s3 = p[6] + p[7]; \
    float s4 = p[8] + p[9], s5 = p[10] + p[11], s6 = p[12] + p[13], s7 = p[14] + p[15]; \
    float psum = ((s0 + s1) + (s2 + s3)) + ((s4 + s5) + (s6 + s7));           \
    lrow += xhalf_sum(psum);                                                  \
    u32 a0 = pktrunc(p[0], p[1]), a1 = pktrunc(p[2], p[3]);                   \
    u32 a2 = pktrunc(p[4], p[5]), a3 = pktrunc(p[6], p[7]);                   \
    u32 b0 = pktrunc(p[8], p[9]), b1 = pktrunc(p[10], p[11]);                 \
    u32 b2 = pktrunc(p[12], p[13]), b3 = pktrunc(p[14], p[15]);               \
    union { bf16x8 v; u32 u[4]; } pa0, pa1;                                   \
    xexchange(hi, a0, a1, a2, a3, pa0.u);                                     \
    xexchange(hi, b0, b1, b2, b3, pa1.u);                                     \
    __builtin_amdgcn_s_setprio(1);                                            \
    _Pragma("unroll") for (int db = 0; db < 4; ++db) {                        \
      acc[db] = __builtin_amdgcn_mfma_f32_32x32x16_bf16(vtf[0][db], pa0.v, acc[db], 0, 0, 0); \
      acc[db] = __builtin_amdgcn_mfma_f32_32x32x16_bf16(vtf[1][db], pa1.v, acc[db], 0, 0, 0); \
    }                                                                         \
    __builtin_amdgcn_s_setprio(0);                                            \
  } while (0)

  // kv loop: tiles kv0 = kvhalf*32, +64, ... while kv0 <= q0 (K double-buffered)
  int kv0 = kvhalf * 32;
  if (kv0 <= q0) {
    LOADK(kfa, kv0);
    while (true) {
      bool more = kv0 + 64 <= q0;
      if (more) LOADK(kfb, kv0 + 64);
      COMPUTE(kfa, kv0);
      if (!more) break;
      kv0 += 64;
      more = kv0 + 64 <= q0;
      if (more) LOADK(kfa, kv0 + 64);
      COMPUTE(kfb, kv0);
      if (!more) break;
      kv0 += 64;
    }
  }
#undef LOADK
#undef COMPUTE

  // ---- merge kv-halves: waves (ti,1) publish partials; waves (ti,0) combine + store ----
  if (kvhalf) {
#pragma unroll
    for (int db = 0; db < 4; ++db)
#pragma unroll
      for (int rq = 0; rq < 4; ++rq) {
        float4 v;
        v.x = acc[db][rq * 4 + 0];
        v.y = acc[db][rq * 4 + 1];
        v.z = acc[db][rq * 4 + 2];
        v.w = acc[db][rq * 4 + 3];
        mO[ti][db * 4 + rq][l] = v;
      }
    mML[ti][0][l] = mrow;
    mML[ti][1][l] = lrow;
  }
  __syncthreads();
  if (!kvhalf) {
    float m1 = mML[ti][0][l], l1 = mML[ti][1][l];
    float mnew = fmaxf(mrow, m1);
    float s0 = exp2f((mrow - mnew) * sm);
    float s1 = exp2f((m1 - mnew) * sm);
    float inv = 1.0f / (lrow * s0 + l1 * s1);
    float f0 = s0 * inv, f1 = s1 * inv;
    u16* ob = AO + (size_t)(b * 2048 + q0 + ql) * 2048 + h * 128 + hi * 4;
#pragma unroll
    for (int db = 0; db < 4; ++db)
#pragma unroll
      for (int rq = 0; rq < 4; ++rq) {
        float4 o1 = mO[ti][db * 4 + rq][l];
        ushort4 o;
        o.x = f2b(acc[db][rq * 4 + 0] * f0 + o1.x * f1);
        o.y = f2b(acc[db][rq * 4 + 1] * f0 + o1.y * f1);
        o.z = f2b(acc[db][rq * 4 + 2] * f0 + o1.z * f1);
        o.w = f2b(acc[db][rq * 4 + 3] * f0 + o1.w * f1);
        *(ushort4*)(ob + db * 32 + rq * 8) = o;
      }
  }
}

// ---------------- host ----------------
extern "C" void kernel_launch(void* const* d_in, const int* in_sizes, int n_in,
                              void* d_out, int out_size, void* d_ws, size_t ws_size,
                              hipStream_t stream) {
  const float* X = (const float*)d_in[0];
  const float* Wq = (const float*)d_in[1];
  const float* Wk = (const float*)d_in[2];
  const float* Wv = (const float*)d_in[3];
  const float* Wo = (const float*)d_in[4];

  u16* ws = (u16*)d_ws;
  const size_t nX = 8388608;   // 2*2048*2048
  const size_t nWq = 4194304;  // 2048*2048
  const size_t nWk = 1048576;  // 512*2048
  u16* Xb = ws;
  u16* Wqb = Xb + nX;          // [Wq|Wk|Wv] contiguous = fused 3072x2048 weight
  u16* Wkb = Wqb + nWq;
  u16* Wvb = Wkb + nWk;
  u16* Wob = Wvb + nWk;
  u16* Qb = Wob + nWq;
  u16* Kb = Qb + nX;
  u16* Vtb = Kb + 2097152;
  u16* AOb = Vtb + 2097152;
  if (ws_size < (size_t)(39845888) * 2) return;

  cvt_bf16<<<2048, 256, 0, stream>>>(X, Xb, (int)nX);
  cvt_w4<<<2048, 256, 0, stream>>>(Wq, Wk, Wv, Wo, Wqb);

  // fused QKV projection: C[4096][3072] routed to Q / K / V^T
  gemm_bt<3><<<dim3(24, 32), 256, 0, stream>>>(Xb, Wqb, Qb, 4096, 3072, 2048, Kb, Vtb);

  attn_fwd<<<dim3(32, 32), 256, 0, stream>>>(Qb, Kb, Vtb, AOb);

  // output projection -> fp32 d_out
  gemm_bt<2><<<dim3(16, 32), 256, 0, stream>>>(AOb, Wob, d_out, 4096, 2048, 2048, nullptr, nullptr);
}

// Round 11
// 250.436 us; speedup vs baseline: 3.0879x; 1.1012x over previous
//
#include <hip/hip_runtime.h>

typedef unsigned short u16;
typedef unsigned int u32;
typedef __attribute__((ext_vector_type(4))) float f32x4;
typedef __attribute__((ext_vector_type(16))) float f32x16;
typedef __attribute__((ext_vector_type(8))) short bf16x8;

// Problem sizes (fixed): B=2, S=2048, D=2048, NH=16, NKV=4, HD=128

__device__ __forceinline__ u16 f2b(float f) {
  u32 u = __builtin_bit_cast(u32, f);
  u = (u + 0x7fffu + ((u >> 16) & 1u)) >> 16;  // RNE
  return (u16)u;
}

__device__ __forceinline__ void gload_lds16(const void* g, void* l) {
  __builtin_amdgcn_global_load_lds((const __attribute__((address_space(1))) u32*)g,
                                   (__attribute__((address_space(3))) u32*)l, 16, 0, 0);
}

// ---- cross-half (lane <-> lane^32) exchange via v_permlane32_swap_b32 (VALU pipe) ----
#if __has_builtin(__builtin_amdgcn_permlane32_swap)
#define HAS_PLS 1
__device__ __forceinline__ void pls(u32 x, u32 y, u32& rx, u32& ry) {
  auto r = __builtin_amdgcn_permlane32_swap(x, y, false, false);
  rx = (u32)r[0];
  ry = (u32)r[1];
}
#endif

__device__ __forceinline__ float xhalf_max(float v) {
#ifdef HAS_PLS
  u32 a, b;
  pls(__builtin_bit_cast(u32, v), __builtin_bit_cast(u32, v), a, b);
  return fmaxf(__builtin_bit_cast(float, a), __builtin_bit_cast(float, b));
#else
  return fmaxf(v, __shfl_xor(v, 32));
#endif
}

__device__ __forceinline__ float xhalf_sum(float v) {
#ifdef HAS_PLS
  u32 a, b;
  pls(__builtin_bit_cast(u32, v), __builtin_bit_cast(u32, v), a, b);
  return __builtin_bit_cast(float, a) + __builtin_bit_cast(float, b);
#else
  return v + __shfl_xor(v, 32);
#endif
}

// P-fragment redistribution across lane halves
__device__ __forceinline__ void xexchange(int hi, u32 a0, u32 a1, u32 a2, u32 a3, u32* o) {
#ifdef HAS_PLS
  pls(a0, a2, o[0], o[2]);
  pls(a1, a3, o[1], o[3]);
#else
  u32 xa0 = (u32)__shfl_xor((int)a0, 32), xa1 = (u32)__shfl_xor((int)a1, 32);
  u32 xa2 = (u32)__shfl_xor((int)a2, 32), xa3 = (u32)__shfl_xor((int)a3, 32);
  o[0] = hi ? xa2 : a0;
  o[1] = hi ? xa3 : a1;
  o[2] = hi ? a2 : xa0;
  o[3] = hi ? a3 : xa1;
#endif
}

// truncating bf16 pair pack (P in [0,1]; <=2^-8 rel err, cheap: 3 ops)
__device__ __forceinline__ u32 pktrunc(float lo, float hif) {
  return (__builtin_bit_cast(u32, lo) >> 16) | (__builtin_bit_cast(u32, hif) & 0xffff0000u);
}

// ---------------- fp32 -> bf16 conversion ----------------
__global__ void cvt_bf16(const float* __restrict__ src, u16* __restrict__ dst, int n) {
  int stride = gridDim.x * blockDim.x * 4;
  for (int idx = (blockIdx.x * blockDim.x + threadIdx.x) * 4; idx < n; idx += stride) {
    float4 v = *(const float4*)(src + idx);
    ushort4 o;
    o.x = f2b(v.x); o.y = f2b(v.y); o.z = f2b(v.z); o.w = f2b(v.w);
    *(ushort4*)(dst + idx) = o;
  }
}

// fused weight conversion: dst = [Wq | Wk | Wv | Wo] contiguous
__global__ void cvt_w4(const float* __restrict__ Wq, const float* __restrict__ Wk,
                       const float* __restrict__ Wv, const float* __restrict__ Wo,
                       u16* __restrict__ dst) {
  const int total = 10485760;
  int stride = gridDim.x * blockDim.x * 4;
  for (int idx = (blockIdx.x * blockDim.x + threadIdx.x) * 4; idx < total; idx += stride) {
    const float* src;
    int off;
    if (idx < 4194304) { src = Wq; off = idx; }
    else if (idx < 5242880) { src = Wk; off = idx - 4194304; }
    else if (idx < 6291456) { src = Wv; off = idx - 5242880; }
    else { src = Wo; off = idx - 6291456; }
    float4 v = *(const float4*)(src + off);
    ushort4 o;
    o.x = f2b(v.x); o.y = f2b(v.y); o.z = f2b(v.z); o.w = f2b(v.w);
    *(ushort4*)(dst + idx) = o;
  }
}

// ---------------- GEMM: C[M,N] = A[M,K] * B[N,K]^T ----------------
// OUT_MODE: 0 = bf16 row-major; 2 = fp32 row-major; 3 = fused QKV routing.
// Mode 3 writes K and V in MFMA-FRAGMENT order so attn loads are fully coalesced:
//   Kf[((b*4+kvh)*64 + kvt)*8 + ck][lane = hi*32+ql][j]   (512 u16 per ck-block)
//   Vf[(((b*4+kvh)*64 + kvt)*2 + ks)*4 + db][lane][j]
template<int OUT_MODE>
__global__ __launch_bounds__(256) void gemm_bt(const u16* __restrict__ A, const u16* __restrict__ B,
                                               void* __restrict__ Cout, int M, int N, int Kd,
                                               u16* __restrict__ Kout, u16* __restrict__ Vtout) {
  __shared__ u16 sA[128 * 32];
  __shared__ u16 sB[128 * 32];
  const int tid = threadIdx.x;
  const int l = tid & 63, w = tid >> 6;
  const int wr = w >> 1, wc = w & 1;
  const int g = l >> 4, c = l & 15;
  const int tm = blockIdx.y * 128, tn = blockIdx.x * 128;

  f32x4 acc[4][4] = {};

  const int r0 = tid >> 2, cc = (tid & 3) << 3;

  for (int k0 = 0; k0 < Kd; k0 += 32) {
    __syncthreads();
    {
      const u16* srcA0 = A + (size_t)(tm + r0) * Kd + k0 + cc;
      const u16* srcB0 = B + (size_t)(tn + r0) * Kd + k0 + cc;
      gload_lds16(srcA0, (char*)sA + w * 1024);
      gload_lds16(srcB0, (char*)sB + w * 1024);
      gload_lds16(srcA0 + (size_t)64 * Kd, (char*)sA + 4096 + w * 1024);
      gload_lds16(srcB0 + (size_t)64 * Kd, (char*)sB + 4096 + w * 1024);
    }
    __syncthreads();

    bf16x8 af[4], bfr[4];
#pragma unroll
    for (int m = 0; m < 4; ++m)
      af[m] = *(const bf16x8*)(sA + (wr * 64 + m * 16 + c) * 32 + g * 8);
#pragma unroll
    for (int n = 0; n < 4; ++n)
      bfr[n] = *(const bf16x8*)(sB + (wc * 64 + n * 16 + c) * 32 + g * 8);
#pragma unroll
    for (int m = 0; m < 4; ++m)
#pragma unroll
      for (int n = 0; n < 4; ++n)
        acc[m][n] = __builtin_amdgcn_mfma_f32_16x16x32_bf16(af[m], bfr[n], acc[m][n], 0, 0, 0);
  }

#pragma unroll
  for (int m = 0; m < 4; ++m)
#pragma unroll
    for (int n = 0; n < 4; ++n)
#pragma unroll
      for (int i = 0; i < 4; ++i) {
        int row = tm + wr * 64 + m * 16 + g * 4 + i;
        int col = tn + wc * 64 + n * 16 + c;
        float v = acc[m][n][i];
        if constexpr (OUT_MODE == 2) {
          ((float*)Cout)[(size_t)row * N + col] = v;
        } else if constexpr (OUT_MODE == 0) {
          ((u16*)Cout)[(size_t)row * N + col] = f2b(v);
        } else {
          int bb = row >> 11, s = row & 2047;
          if (tn < 2048) {
            ((u16*)Cout)[(size_t)row * 2048 + col] = f2b(v);          // Q row-major
          } else if (tn < 2560) {
            // K fragment order: k = ck*16 + hi*8 + j; kv = s
            int e = col - 2048;
            int kvh_ = e >> 7, k = e & 127;
            int ck_ = k >> 4, hi_ = (k >> 3) & 1, j_ = k & 7;
            size_t dst = ((((size_t)(bb * 4 + kvh_) * 64 + (s >> 5)) * 8 + ck_) * 64
                          + hi_ * 32 + (s & 31)) * 8 + j_;
            Kout[dst] = f2b(v);
          } else {
            // V^T fragment order: row(d) = db*32+ql; kv = s = kvt*32 + ks*16 + hi*8 + j
            int e = col - 2560;
            int kvh_ = e >> 7, d = e & 127;
            int db_ = d >> 5, qld = d & 31;
            int ks_ = (s >> 4) & 1, hi_ = (s >> 3) & 1, j_ = s & 7;
            size_t dst = ((((size_t)(bb * 4 + kvh_) * 64 + (s >> 5)) * 2 + ks_) * 4 + db_) * 512
                         + (size_t)hi_ * 256 + qld * 8 + j_;
            Vtout[dst] = f2b(v);
          }
        }
      }
}

// ---------------- causal GQA flash attention: 32x32 swapped-operand + balanced KV-split ----
// grid (32, 32), block 256 (4 waves). Wave w = (ti = w&1, kvhalf = w>>1).
// q-subtile t = ti ? 63-x : x  -> every block does exactly 65 kv-tile units.
// K/V are in MFMA-fragment order: every load = 64 lanes x contiguous 16 B (1 KB coalesced),
// eliminating the TA transaction scatter that capped rounds 5-10 at ~137 us.
// NOTE: min-waves arg MUST be 2 — (256,4) caps VGPR at 64 and spills (round 8: 5x regression).
__global__ __launch_bounds__(256, 2) void attn_fwd(const u16* __restrict__ Q, const u16* __restrict__ Kf,
                                                   const u16* __restrict__ Vf, u16* __restrict__ AO) {
  const int l = threadIdx.x & 63, w = threadIdx.x >> 6;
  const int ql = l & 31, hi = l >> 5;
  const int bh = blockIdx.y;
  const int b = bh >> 4, h = bh & 15;
  const int kvh = h >> 2;

  __shared__ float4 mO[2][16][64];   // [ti][elem][lane] — partials from kvhalf=1 waves
  __shared__ float mML[2][2][64];

  const float sm = 0.08838834764831845f * 1.4426950408889634f;  // 1/sqrt(128) * log2(e)

  // fragment-ordered bases: 64 kv-tiles x 4096 u16 per (b,kvh)
  const u16* Kfb = Kf + (size_t)(b * 4 + kvh) * 64 * 4096 + l * 8;
  const u16* Vfb = Vf + (size_t)(b * 4 + kvh) * 64 * 4096 + l * 8;

  const int ti = w & 1, kvhalf = w >> 1;
  const int t = ti ? (63 - (int)blockIdx.x) : (int)blockIdx.x;
  const int q0 = t * 32;

  // Q fragments (B-operand of QK: col=q=lane&31, k = ck*16 + hi*8 + j)
  bf16x8 qf[8];
  {
    const u16* qb = Q + ((size_t)(b * 2048 + q0 + ql)) * 2048 + h * 128 + hi * 8;
#pragma unroll
    for (int ck = 0; ck < 8; ++ck) qf[ck] = *(const bf16x8*)(qb + ck * 16);
  }

  f32x16 acc[4] = {};  // O^T[d = db*32 + crow(r)][q = q0 + (lane&31)]
  float mrow = -1e30f, lrow = 0.f;

  bf16x8 kfa[8], kfb[8];

#define LOADK(KF, KV0)                                                        \
  do {                                                                        \
    const u16* kb_ = Kfb + (size_t)((KV0) >> 5) * 4096;                       \
    _Pragma("unroll") for (int ck = 0; ck < 8; ++ck)                          \
        KF[ck] = *(const bf16x8*)(kb_ + ck * 512);                            \
  } while (0)

#define COMPUTE(KF, KV0)                                                      \
  do {                                                                        \
    bf16x8 vtf[2][4];                                                         \
    {                                                                         \
      const u16* vb_ = Vfb + (size_t)((KV0) >> 5) * 4096;                     \
      _Pragma("unroll") for (int ks = 0; ks < 2; ++ks)                        \
      _Pragma("unroll") for (int db = 0; db < 4; ++db)                        \
          vtf[ks][db] = *(const bf16x8*)(vb_ + (ks * 4 + db) * 512);          \
    }                                                                         \
    f32x16 sacc = {};                                                         \
    __builtin_amdgcn_s_setprio(1);                                            \
    _Pragma("unroll") for (int ck = 0; ck < 8; ++ck)                          \
        sacc = __builtin_amdgcn_mfma_f32_32x32x16_bf16(KF[ck], qf[ck], sacc, 0, 0, 0); \
    __builtin_amdgcn_s_setprio(0);                                            \
    if ((KV0) == q0) { /* diagonal: mask kv > q */                            \
      _Pragma("unroll") for (int r = 0; r < 16; ++r) {                        \
        int crow = (r & 3) + 8 * (r >> 2) + 4 * hi;                           \
        if (crow > ql) sacc[r] = -1e30f;                                      \
      }                                                                       \
    }                                                                         \
    float t0 = fmaxf(sacc[0], sacc[1]), t1 = fmaxf(sacc[2], sacc[3]);         \
    float t2 = fmaxf(sacc[4], sacc[5]), t3 = fmaxf(sacc[6], sacc[7]);         \
    float t4 = fmaxf(sacc[8], sacc[9]), t5 = fmaxf(sacc[10], sacc[11]);       \
    float t6 = fmaxf(sacc[12], sacc[13]), t7 = fmaxf(sacc[14], sacc[15]);     \
    float mx = fmaxf(fmaxf(fmaxf(t0, t1), fmaxf(t2, t3)),                     \
                     fmaxf(fmaxf(t4, t5), fmaxf(t6, t7)));                    \
    mx = xhalf_max(mx);                                                       \
    float p[16];                                                              \
    _Pragma("unroll") for (int r = 0; r < 16; ++r)                            \
        p[r] = exp2f((sacc[r] - mrow) * sm);                                  \
    if (!__all((mx - mrow) * sm <= 8.0f)) { /* T13 defer-max */               \
      float mnew = fmaxf(mrow, mx);                                           \
      float rs = exp2f((mrow - mnew) * sm);                                   \
      mrow = mnew;                                                            \
      lrow *= rs;                                                             \
      _Pragma("unroll") for (int db = 0; db < 4; ++db)                        \
      _Pragma("unroll") for (int r = 0; r < 16; ++r) acc[db][r] *= rs;        \
      _Pragma("unroll") for (int r = 0; r < 16; ++r)                          \
          p[r] = exp2f((sacc[r] - mrow) * sm);                                \
    }                                                                         \
    float s0 = p[0] + p[1], s1 = p[2] + p[3], s2 = p[4] + p[5], s3 = p[6] + p[7]; \
    float s4 = p[8] + p[9], s5 = p[10] + p[11], s6 = p[12] + p[13], s7 = p[14] + p[15]; \
    float psum = ((s0 + s1) + (s2 + s3)) + ((s4 + s5) + (s6 + s7));           \
    lrow += xhalf_sum(psum);                                                  \
    u32 a0 = pktrunc(p[0], p[1]), a1 = pktrunc(p[2], p[3]);                   \
    u32 a2 = pktrunc(p[4], p[5]), a3 = pktrunc(p[6], p[7]);                   \
    u32 b0 = pktrunc(p[8], p[9]), b1 = pktrunc(p[10], p[11]);                 \
    u32 b2 = pktrunc(p[12], p[13]), b3 = pktrunc(p[14], p[15]);               \
    union { bf16x8 v; u32 u[4]; } pa0, pa1;                                   \
    xexchange(hi, a0, a1, a2, a3, pa0.u);                                     \
    xexchange(hi, b0, b1, b2, b3, pa1.u);                                     \
    __builtin_amdgcn_s_setprio(1);                                            \
    _Pragma("unroll") for (int db = 0; db < 4; ++db) {                        \
      acc[db] = __builtin_amdgcn_mfma_f32_32x32x16_bf16(vtf[0][db], pa0.v, acc[db], 0, 0, 0); \
      acc[db] = __builtin_amdgcn_mfma_f32_32x32x16_bf16(vtf[1][db], pa1.v, acc[db], 0, 0, 0); \
    }                                                                         \
    __builtin_amdgcn_s_setprio(0);                                            \
  } while (0)

  // kv loop: tiles kv0 = kvhalf*32, +64, ... while kv0 <= q0 (K double-buffered)
  int kv0 = kvhalf * 32;
  if (kv0 <= q0) {
    LOADK(kfa, kv0);
    while (true) {
      bool more = kv0 + 64 <= q0;
      if (more) LOADK(kfb, kv0 + 64);
      COMPUTE(kfa, kv0);
      if (!more) break;
      kv0 += 64;
      more = kv0 + 64 <= q0;
      if (more) LOADK(kfa, kv0 + 64);
      COMPUTE(kfb, kv0);
      if (!more) break;
      kv0 += 64;
    }
  }
#undef LOADK
#undef COMPUTE

  // ---- merge kv-halves: waves (ti,1) publish partials; waves (ti,0) combine + store ----
  if (kvhalf) {
#pragma unroll
    for (int db = 0; db < 4; ++db)
#pragma unroll
      for (int rq = 0; rq < 4; ++rq) {
        float4 v;
        v.x = acc[db][rq * 4 + 0];
        v.y = acc[db][rq * 4 + 1];
        v.z = acc[db][rq * 4 + 2];
        v.w = acc[db][rq * 4 + 3];
        mO[ti][db * 4 + rq][l] = v;
      }
    mML[ti][0][l] = mrow;
    mML[ti][1][l] = lrow;
  }
  __syncthreads();
  if (!kvhalf) {
    float m1 = mML[ti][0][l], l1 = mML[ti][1][l];
    float mnew = fmaxf(mrow, m1);
    float s0 = exp2f((mrow - mnew) * sm);
    float s1 = exp2f((m1 - mnew) * sm);
    float inv = 1.0f / (lrow * s0 + l1 * s1);
    float f0 = s0 * inv, f1 = s1 * inv;
    u16* ob = AO + (size_t)(b * 2048 + q0 + ql) * 2048 + h * 128 + hi * 4;
#pragma unroll
    for (int db = 0; db < 4; ++db)
#pragma unroll
      for (int rq = 0; rq < 4; ++rq) {
        float4 o1 = mO[ti][db * 4 + rq][l];
        ushort4 o;
        o.x = f2b(acc[db][rq * 4 + 0] * f0 + o1.x * f1);
        o.y = f2b(acc[db][rq * 4 + 1] * f0 + o1.y * f1);
        o.z = f2b(acc[db][rq * 4 + 2] * f0 + o1.z * f1);
        o.w = f2b(acc[db][rq * 4 + 3] * f0 + o1.w * f1);
        *(ushort4*)(ob + db * 32 + rq * 8) = o;
      }
  }
}

// ---------------- host ----------------
extern "C" void kernel_launch(void* const* d_in, const int* in_sizes, int n_in,
                              void* d_out, int out_size, void* d_ws, size_t ws_size,
                              hipStream_t stream) {
  const float* X = (const float*)d_in[0];
  const float* Wq = (const float*)d_in[1];
  const float* Wk = (const float*)d_in[2];
  const float* Wv = (const float*)d_in[3];
  const float* Wo = (const float*)d_in[4];

  u16* ws = (u16*)d_ws;
  const size_t nX = 8388608;   // 2*2048*2048
  const size_t nWq = 4194304;  // 2048*2048
  const size_t nWk = 1048576;  // 512*2048
  u16* Xb = ws;
  u16* Wqb = Xb + nX;          // [Wq|Wk|Wv] contiguous = fused 3072x2048 weight
  u16* Wkb = Wqb + nWq;
  u16* Wvb = Wkb + nWk;
  u16* Wob = Wvb + nWk;
  u16* Qb = Wob + nWq;
  u16* Kfb = Qb + nX;          // K in fragment order (2M u16)
  u16* Vfb = Kfb + 2097152;    // V in fragment order (2M u16)
  u16* AOb = Vfb + 2097152;
  if (ws_size < (size_t)(39845888) * 2) return;

  cvt_bf16<<<2048, 256, 0, stream>>>(X, Xb, (int)nX);
  cvt_w4<<<2048, 256, 0, stream>>>(Wq, Wk, Wv, Wo, Wqb);

  // fused QKV projection: C[4096][3072] routed to Q / K-frag / V-frag
  gemm_bt<3><<<dim3(24, 32), 256, 0, stream>>>(Xb, Wqb, Qb, 4096, 3072, 2048, Kfb, Vfb);

  attn_fwd<<<dim3(32, 32), 256, 0, stream>>>(Qb, Kfb, Vfb, AOb);

  // output projection -> fp32 d_out
  gemm_bt<2><<<dim3(16, 32), 256, 0, stream>>>(AOb, Wob, d_out, 4096, 2048, 2048, nullptr, nullptr);
}

// Round 12
// 216.190 us; speedup vs baseline: 3.5770x; 1.1584x over previous
//
#include <hip/hip_runtime.h>

typedef unsigned short u16;
typedef unsigned int u32;
typedef __attribute__((ext_vector_type(4))) float f32x4;
typedef __attribute__((ext_vector_type(16))) float f32x16;
typedef __attribute__((ext_vector_type(8))) short bf16x8;

// Problem sizes (fixed): B=2, S=2048, D=2048, NH=16, NKV=4, HD=128

__device__ __forceinline__ u16 f2b(float f) {
  u32 u = __builtin_bit_cast(u32, f);
  u = (u + 0x7fffu + ((u >> 16) & 1u)) >> 16;  // RNE
  return (u16)u;
}

__device__ __forceinline__ void gload_lds16(const void* g, void* l) {
  __builtin_amdgcn_global_load_lds((const __attribute__((address_space(1))) u32*)g,
                                   (__attribute__((address_space(3))) u32*)l, 16, 0, 0);
}

// ---- cross-half (lane <-> lane^32) exchange via v_permlane32_swap_b32 (VALU pipe) ----
#if __has_builtin(__builtin_amdgcn_permlane32_swap)
#define HAS_PLS 1
__device__ __forceinline__ void pls(u32 x, u32 y, u32& rx, u32& ry) {
  auto r = __builtin_amdgcn_permlane32_swap(x, y, false, false);
  rx = (u32)r[0];
  ry = (u32)r[1];
}
#endif

__device__ __forceinline__ float xhalf_max(float v) {
#ifdef HAS_PLS
  u32 a, b;
  pls(__builtin_bit_cast(u32, v), __builtin_bit_cast(u32, v), a, b);
  return fmaxf(__builtin_bit_cast(float, a), __builtin_bit_cast(float, b));
#else
  return fmaxf(v, __shfl_xor(v, 32));
#endif
}

__device__ __forceinline__ float xhalf_sum(float v) {
#ifdef HAS_PLS
  u32 a, b;
  pls(__builtin_bit_cast(u32, v), __builtin_bit_cast(u32, v), a, b);
  return __builtin_bit_cast(float, a) + __builtin_bit_cast(float, b);
#else
  return v + __shfl_xor(v, 32);
#endif
}

// P-fragment redistribution across lane halves
__device__ __forceinline__ void xexchange(int hi, u32 a0, u32 a1, u32 a2, u32 a3, u32* o) {
#ifdef HAS_PLS
  pls(a0, a2, o[0], o[2]);
  pls(a1, a3, o[1], o[3]);
#else
  u32 xa0 = (u32)__shfl_xor((int)a0, 32), xa1 = (u32)__shfl_xor((int)a1, 32);
  u32 xa2 = (u32)__shfl_xor((int)a2, 32), xa3 = (u32)__shfl_xor((int)a3, 32);
  o[0] = hi ? xa2 : a0;
  o[1] = hi ? xa3 : a1;
  o[2] = hi ? a2 : xa0;
  o[3] = hi ? a3 : xa1;
#endif
}

// truncating bf16 pair pack (P in [0,1]; <=2^-8 rel err, cheap: 3 ops)
__device__ __forceinline__ u32 pktrunc(float lo, float hif) {
  return (__builtin_bit_cast(u32, lo) >> 16) | (__builtin_bit_cast(u32, hif) & 0xffff0000u);
}

// ---------------- fp32 -> bf16 conversion ----------------
__global__ void cvt_bf16(const float* __restrict__ src, u16* __restrict__ dst, int n) {
  int stride = gridDim.x * blockDim.x * 4;
  for (int idx = (blockIdx.x * blockDim.x + threadIdx.x) * 4; idx < n; idx += stride) {
    float4 v = *(const float4*)(src + idx);
    ushort4 o;
    o.x = f2b(v.x); o.y = f2b(v.y); o.z = f2b(v.z); o.w = f2b(v.w);
    *(ushort4*)(dst + idx) = o;
  }
}

// fused weight conversion: dst = [Wq | Wk | Wv | Wo] contiguous
__global__ void cvt_w4(const float* __restrict__ Wq, const float* __restrict__ Wk,
                       const float* __restrict__ Wv, const float* __restrict__ Wo,
                       u16* __restrict__ dst) {
  const int total = 10485760;
  int stride = gridDim.x * blockDim.x * 4;
  for (int idx = (blockIdx.x * blockDim.x + threadIdx.x) * 4; idx < total; idx += stride) {
    const float* src;
    int off;
    if (idx < 4194304) { src = Wq; off = idx; }
    else if (idx < 5242880) { src = Wk; off = idx - 4194304; }
    else if (idx < 6291456) { src = Wv; off = idx - 5242880; }
    else { src = Wo; off = idx - 6291456; }
    float4 v = *(const float4*)(src + off);
    ushort4 o;
    o.x = f2b(v.x); o.y = f2b(v.y); o.z = f2b(v.z); o.w = f2b(v.w);
    *(ushort4*)(dst + idx) = o;
  }
}

// ---------------- GEMM: C[M,N] = A[M,K] * B[N,K]^T ----------------
// OUT_MODE: 0 = bf16 row-major; 2 = fp32 row-major; 3 = fused QKV routing.
// Mode 3 writes K and V in MFMA-FRAGMENT order. The fragment destination of a
// 128x128 K/V tile is 4 contiguous 8KB chunks, so the epilogue stages the
// permutation through LDS (32 KB) and stores fully coalesced (round 11's direct
// u16 scatter cost ~47 us of L2 transactions).
//   Kf[((b*4+kvh)*64 + kvt)*8 + ck][lane = hi*32+ql][j]
//   Vf[(((b*4+kvh)*64 + kvt)*2 + ks)*4 + db][lane][j]
template<int OUT_MODE>
__global__ __launch_bounds__(256) void gemm_bt(const u16* __restrict__ A, const u16* __restrict__ B,
                                               void* __restrict__ Cout, int M, int N, int Kd,
                                               u16* __restrict__ Kout, u16* __restrict__ Vtout) {
  __shared__ u16 smem[(OUT_MODE == 3) ? 16384 : 8192];
  u16* sA = smem;
  u16* sB = smem + 4096;
  const int tid = threadIdx.x;
  const int l = tid & 63, w = tid >> 6;
  const int wr = w >> 1, wc = w & 1;
  const int g = l >> 4, c = l & 15;
  const int tm = blockIdx.y * 128, tn = blockIdx.x * 128;

  f32x4 acc[4][4] = {};

  const int r0 = tid >> 2, cc = (tid & 3) << 3;

  for (int k0 = 0; k0 < Kd; k0 += 32) {
    __syncthreads();
    {
      const u16* srcA0 = A + (size_t)(tm + r0) * Kd + k0 + cc;
      const u16* srcB0 = B + (size_t)(tn + r0) * Kd + k0 + cc;
      gload_lds16(srcA0, (char*)sA + w * 1024);
      gload_lds16(srcB0, (char*)sB + w * 1024);
      gload_lds16(srcA0 + (size_t)64 * Kd, (char*)sA + 4096 + w * 1024);
      gload_lds16(srcB0 + (size_t)64 * Kd, (char*)sB + 4096 + w * 1024);
    }
    __syncthreads();

    bf16x8 af[4], bfr[4];
#pragma unroll
    for (int m = 0; m < 4; ++m)
      af[m] = *(const bf16x8*)(sA + (wr * 64 + m * 16 + c) * 32 + g * 8);
#pragma unroll
    for (int n = 0; n < 4; ++n)
      bfr[n] = *(const bf16x8*)(sB + (wc * 64 + n * 16 + c) * 32 + g * 8);
#pragma unroll
    for (int m = 0; m < 4; ++m)
#pragma unroll
      for (int n = 0; n < 4; ++n)
        acc[m][n] = __builtin_amdgcn_mfma_f32_16x16x32_bf16(af[m], bfr[n], acc[m][n], 0, 0, 0);
  }

  if constexpr (OUT_MODE == 3) {
    if (tn >= 2048) {
      // ---- K/V fragment-order epilogue via LDS staging ----
      const bool isK = tn < 2560;
      __syncthreads();  // all MFMA LDS reads done before smem reuse
#pragma unroll
      for (int m = 0; m < 4; ++m)
#pragma unroll
        for (int n = 0; n < 4; ++n)
#pragma unroll
          for (int i = 0; i < 4; ++i) {
            int lr = wr * 64 + m * 16 + g * 4 + i;   // local row (kv position s)
            int lc = wc * 64 + n * 16 + c;           // local col (k or d)
            int off;
            if (isK)
              off = ((lr >> 5) << 12) + ((lc >> 4) << 9) + (((lc >> 3) & 1) << 8) +
                    ((lr & 31) << 3) + (lc & 7);
            else
              off = ((lr >> 5) << 12) + (((lr >> 4) & 1) << 11) + ((lc >> 5) << 9) +
                    (((lr >> 3) & 1) << 8) + ((lc & 31) << 3) + (lr & 7);
            smem[off] = f2b(acc[m][n][i]);
          }
      __syncthreads();
      const int e0 = tn - (isK ? 2048 : 2560);
      const int bb = tm >> 11;
      u16* dstbase = (isK ? Kout : Vtout) +
                     ((((size_t)(bb * 4 + (e0 >> 7)) * 64 + ((tm & 2047) >> 5))) << 12);
#pragma unroll
      for (int ps = 0; ps < 8; ++ps) {
        int idx = ps * 2048 + tid * 8;
        *(bf16x8*)(dstbase + idx) = *(const bf16x8*)(smem + idx);
      }
      return;
    }
  }

#pragma unroll
  for (int m = 0; m < 4; ++m)
#pragma unroll
    for (int n = 0; n < 4; ++n)
#pragma unroll
      for (int i = 0; i < 4; ++i) {
        int row = tm + wr * 64 + m * 16 + g * 4 + i;
        int col = tn + wc * 64 + n * 16 + c;
        float v = acc[m][n][i];
        if constexpr (OUT_MODE == 2) {
          ((float*)Cout)[(size_t)row * N + col] = v;
        } else {
          ((u16*)Cout)[(size_t)row * 2048 + col] = f2b(v);  // Q / bf16 row-major (ld 2048)
        }
      }
}

// ---------------- causal GQA flash attention: 32x32 swapped-operand + balanced KV-split ----
// grid (32, 32), block 256 (4 waves). Wave w = (ti = w&1, kvhalf = w>>1).
// q-subtile t = ti ? 63-x : x  -> every block does exactly 65 kv-tile units.
// K/V are in MFMA-fragment order: every load = 64 lanes x contiguous 16 B (1 KB coalesced).
// NOTE: min-waves arg MUST be 2 — (256,4) caps VGPR at 64 and spills (round 8: 5x regression).
__global__ __launch_bounds__(256, 2) void attn_fwd(const u16* __restrict__ Q, const u16* __restrict__ Kf,
                                                   const u16* __restrict__ Vf, u16* __restrict__ AO) {
  const int l = threadIdx.x & 63, w = threadIdx.x >> 6;
  const int ql = l & 31, hi = l >> 5;
  const int bh = blockIdx.y;
  const int b = bh >> 4, h = bh & 15;
  const int kvh = h >> 2;

  __shared__ float4 mO[2][16][64];   // [ti][elem][lane] — partials from kvhalf=1 waves
  __shared__ float mML[2][2][64];

  const float sm = 0.08838834764831845f * 1.4426950408889634f;  // 1/sqrt(128) * log2(e)

  // fragment-ordered bases: 64 kv-tiles x 4096 u16 per (b,kvh)
  const u16* Kfb = Kf + (size_t)(b * 4 + kvh) * 64 * 4096 + l * 8;
  const u16* Vfb = Vf + (size_t)(b * 4 + kvh) * 64 * 4096 + l * 8;

  const int ti = w & 1, kvhalf = w >> 1;
  const int t = ti ? (63 - (int)blockIdx.x) : (int)blockIdx.x;
  const int q0 = t * 32;

  // Q fragments (B-operand of QK: col=q=lane&31, k = ck*16 + hi*8 + j)
  bf16x8 qf[8];
  {
    const u16* qb = Q + ((size_t)(b * 2048 + q0 + ql)) * 2048 + h * 128 + hi * 8;
#pragma unroll
    for (int ck = 0; ck < 8; ++ck) qf[ck] = *(const bf16x8*)(qb + ck * 16);
  }

  f32x16 acc[4] = {};  // O^T[d = db*32 + crow(r)][q = q0 + (lane&31)]
  float mrow = -1e30f, lrow = 0.f;

  bf16x8 kfa[8], kfb[8];

#define LOADK(KF, KV0)                                                        \
  do {                                                                        \
    const u16* kb_ = Kfb + (size_t)((KV0) >> 5) * 4096;                       \
    _Pragma("unroll") for (int ck = 0; ck < 8; ++ck)                          \
        KF[ck] = *(const bf16x8*)(kb_ + ck * 512);                            \
  } while (0)

#define COMPUTE(KF, KV0)                                                      \
  do {                                                                        \
    bf16x8 vtf[2][4];                                                         \
    {                                                                         \
      const u16* vb_ = Vfb + (size_t)((KV0) >> 5) * 4096;                     \
      _Pragma("unroll") for (int ks = 0; ks < 2; ++ks)                        \
      _Pragma("unroll") for (int db = 0; db < 4; ++db)                        \
          vtf[ks][db] = *(const bf16x8*)(vb_ + (ks * 4 + db) * 512);          \
    }                                                                         \
    f32x16 sacc = {};                                                         \
    __builtin_amdgcn_s_setprio(1);                                            \
    _Pragma("unroll") for (int ck = 0; ck < 8; ++ck)                          \
        sacc = __builtin_amdgcn_mfma_f32_32x32x16_bf16(KF[ck], qf[ck], sacc, 0, 0, 0); \
    __builtin_amdgcn_s_setprio(0);                                            \
    if ((KV0) == q0) { /* diagonal: mask kv > q */                            \
      _Pragma("unroll") for (int r = 0; r < 16; ++r) {                        \
        int crow = (r & 3) + 8 * (r >> 2) + 4 * hi;                           \
        if (crow > ql) sacc[r] = -1e30f;                                      \
      }                                                                       \
    }                                                                         \
    float t0 = fmaxf(sacc[0], sacc[1]), t1 = fmaxf(sacc[2], sacc[3]);         \
    float t2 = fmaxf(sacc[4], sacc[5]), t3 = fmaxf(sacc[6], sacc[7]);         \
    float t4 = fmaxf(sacc[8], sacc[9]), t5 = fmaxf(sacc[10], sacc[11]);       \
    float t6 = fmaxf(sacc[12], sacc[13]), t7 = fmaxf(sacc[14], sacc[15]);     \
    float mx = fmaxf(fmaxf(fmaxf(t0, t1), fmaxf(t2, t3)),                     \
                     fmaxf(fmaxf(t4, t5), fmaxf(t6, t7)));                    \
    mx = xhalf_max(mx);                                                       \
    float p[16];                                                              \
    _Pragma("unroll") for (int r = 0; r < 16; ++r)                            \
        p[r] = exp2f((sacc[r] - mrow) * sm);                                  \
    if (!__all((mx - mrow) * sm <= 8.0f)) { /* T13 defer-max */               \
      float mnew = fmaxf(mrow, mx);                                           \
      float rs = exp2f((mrow - mnew) * sm);                                   \
      mrow = mnew;                                                            \
      lrow *= rs;                                                             \
      _Pragma("unroll") for (int db = 0; db < 4; ++db)                        \
      _Pragma("unroll") for (int r = 0; r < 16; ++r) acc[db][r] *= rs;        \
      _Pragma("unroll") for (int r = 0; r < 16; ++r)                          \
          p[r] = exp2f((sacc[r] - mrow) * sm);                                \
    }                                                                         \
    float s0 = p[0] + p[1], s1 = p[2] + p[3], s2 = p[4] + p[5], s3 = p[6] + p[7]; \
    float s4 = p[8] + p[9], s5 = p[10] + p[11], s6 = p[12] + p[13], s7 = p[14] + p[15]; \
    float psum = ((s0 + s1) + (s2 + s3)) + ((s4 + s5) + (s6 + s7));           \
    lrow += xhalf_sum(psum);                                                  \
    u32 a0 = pktrunc(p[0], p[1]), a1 = pktrunc(p[2], p[3]);                   \
    u32 a2 = pktrunc(p[4], p[5]), a3 = pktrunc(p[6], p[7]);                   \
    u32 b0 = pktrunc(p[8], p[9]), b1 = pktrunc(p[10], p[11]);                 \
    u32 b2 = pktrunc(p[12], p[13]), b3 = pktrunc(p[14], p[15]);               \
    union { bf16x8 v; u32 u[4]; } pa0, pa1;                                   \
    xexchange(hi, a0, a1, a2, a3, pa0.u);                                     \
    xexchange(hi, b0, b1, b2, b3, pa1.u);                                     \
    __builtin_amdgcn_s_setprio(1);                                            \
    _Pragma("unroll") for (int db = 0; db < 4; ++db) {                        \
      acc[db] = __builtin_amdgcn_mfma_f32_32x32x16_bf16(vtf[0][db], pa0.v, acc[db], 0, 0, 0); \
      acc[db] = __builtin_amdgcn_mfma_f32_32x32x16_bf16(vtf[1][db], pa1.v, acc[db], 0, 0, 0); \
    }                                                                         \
    __builtin_amdgcn_s_setprio(0);                                            \
  } while (0)

  // kv loop: tiles kv0 = kvhalf*32, +64, ... while kv0 <= q0 (K double-buffered)
  int kv0 = kvhalf * 32;
  if (kv0 <= q0) {
    LOADK(kfa, kv0);
    while (true) {
      bool more = kv0 + 64 <= q0;
      if (more) LOADK(kfb, kv0 + 64);
      COMPUTE(kfa, kv0);
      if (!more) break;
      kv0 += 64;
      more = kv0 + 64 <= q0;
      if (more) LOADK(kfa, kv0 + 64);
      COMPUTE(kfb, kv0);
      if (!more) break;
      kv0 += 64;
    }
  }
#undef LOADK
#undef COMPUTE

  // ---- merge kv-halves: waves (ti,1) publish partials; waves (ti,0) combine + store ----
  if (kvhalf) {
#pragma unroll
    for (int db = 0; db < 4; ++db)
#pragma unroll
      for (int rq = 0; rq < 4; ++rq) {
        float4 v;
        v.x = acc[db][rq * 4 + 0];
        v.y = acc[db][rq * 4 + 1];
        v.z = acc[db][rq * 4 + 2];
        v.w = acc[db][rq * 4 + 3];
        mO[ti][db * 4 + rq][l] = v;
      }
    mML[ti][0][l] = mrow;
    mML[ti][1][l] = lrow;
  }
  __syncthreads();
  if (!kvhalf) {
    float m1 = mML[ti][0][l], l1 = mML[ti][1][l];
    float mnew = fmaxf(mrow, m1);
    float s0 = exp2f((mrow - mnew) * sm);
    float s1 = exp2f((m1 - mnew) * sm);
    float inv = 1.0f / (lrow * s0 + l1 * s1);
    float f0 = s0 * inv, f1 = s1 * inv;
    u16* ob = AO + (size_t)(b * 2048 + q0 + ql) * 2048 + h * 128 + hi * 4;
#pragma unroll
    for (int db = 0; db < 4; ++db)
#pragma unroll
      for (int rq = 0; rq < 4; ++rq) {
        float4 o1 = mO[ti][db * 4 + rq][l];
        ushort4 o;
        o.x = f2b(acc[db][rq * 4 + 0] * f0 + o1.x * f1);
        o.y = f2b(acc[db][rq * 4 + 1] * f0 + o1.y * f1);
        o.z = f2b(acc[db][rq * 4 + 2] * f0 + o1.z * f1);
        o.w = f2b(acc[db][rq * 4 + 3] * f0 + o1.w * f1);
        *(ushort4*)(ob + db * 32 + rq * 8) = o;
      }
  }
}

// ---------------- host ----------------
extern "C" void kernel_launch(void* const* d_in, const int* in_sizes, int n_in,
                              void* d_out, int out_size, void* d_ws, size_t ws_size,
                              hipStream_t stream) {
  const float* X = (const float*)d_in[0];
  const float* Wq = (const float*)d_in[1];
  const float* Wk = (const float*)d_in[2];
  const float* Wv = (const float*)d_in[3];
  const float* Wo = (const float*)d_in[4];

  u16* ws = (u16*)d_ws;
  const size_t nX = 8388608;   // 2*2048*2048
  const size_t nWq = 4194304;  // 2048*2048
  const size_t nWk = 1048576;  // 512*2048
  u16* Xb = ws;
  u16* Wqb = Xb + nX;          // [Wq|Wk|Wv] contiguous = fused 3072x2048 weight
  u16* Wkb = Wqb + nWq;
  u16* Wvb = Wkb + nWk;
  u16* Wob = Wvb + nWk;
  u16* Qb = Wob + nWq;
  u16* Kfb = Qb + nX;          // K in fragment order (2M u16)
  u16* Vfb = Kfb + 2097152;    // V in fragment order (2M u16)
  u16* AOb = Vfb + 2097152;
  if (ws_size < (size_t)(39845888) * 2) return;

  cvt_bf16<<<2048, 256, 0, stream>>>(X, Xb, (int)nX);
  cvt_w4<<<2048, 256, 0, stream>>>(Wq, Wk, Wv, Wo, Wqb);

  // fused QKV projection: C[4096][3072] routed to Q / K-frag / V-frag
  gemm_bt<3><<<dim3(24, 32), 256, 0, stream>>>(Xb, Wqb, Qb, 4096, 3072, 2048, Kfb, Vfb);

  attn_fwd<<<dim3(32, 32), 256, 0, stream>>>(Qb, Kfb, Vfb, AOb);

  // output projection -> fp32 d_out
  gemm_bt<2><<<dim3(16, 32), 256, 0, stream>>>(AOb, Wob, d_out, 4096, 2048, 2048, nullptr, nullptr);
}